// Round 6
// baseline (383.022 us; speedup 1.0000x reference)
//
#include <hip/hip_runtime.h>
#include <math.h>

#define HIDC 64
#define HD 512  // combined xl|xr channels per node (bf16)

typedef unsigned int uint32;
using short8 = __attribute__((ext_vector_type(8))) short;
using f32x4 = __attribute__((ext_vector_type(4))) float;

__device__ inline float ubits(uint32 u) { return __builtin_bit_cast(float, u); }
__device__ inline unsigned short f2bf(float x) {
  uint32 u = __builtin_bit_cast(uint32, x);
  return (unsigned short)((u + 0x7fffu + ((u >> 16) & 1u)) >> 16);
}
__device__ inline uint32 cvtpk_bf16(float lo, float hi) {  // RTNE, matches f2bf
  uint32 r;
  asm("v_cvt_pk_bf16_f32 %0, %1, %2" : "=v"(r) : "v"(lo), "v"(hi));
  return r;
}

template <int CTRL>
__device__ inline float dpp_add(float x) {
  int xi = __builtin_bit_cast(int, x);
  int s = __builtin_amdgcn_update_dpp(0, xi, CTRL, 0xf, 0xf, true);
  return x + __builtin_bit_cast(float, s);
}

// ---------------- prep: edge count (CSR) + weight bf16 pack, one kernel ----------------
__global__ void prep_kernel(const int* __restrict__ ei, int E, int N, int eb,
                            int* __restrict__ counts,
                            const float* __restrict__ Wl1, const float* __restrict__ Wr1,
                            const float* __restrict__ Wl2, const float* __restrict__ Wr2,
                            unsigned short* __restrict__ Wc1, unsigned short* __restrict__ Wc2) {
  int blk = blockIdx.x;
  if (blk < eb) {
    int e = blk * blockDim.x + threadIdx.x;
    int etot = E + N;
    if (e >= etot) return;
    int dst = (e < E) ? ei[E + e] : (e - E);
    atomicAdd(&counts[dst], 1);
  } else {
    int j = (blk - eb) * blockDim.x + threadIdx.x;  // [0, 24576) float4s
    const float* src;
    unsigned short* dst;
    int local;
    if (j < 8192) { src = Wl1; dst = Wc1; local = j; }
    else if (j < 16384) { src = Wr1; dst = Wc1 + 32768; local = j - 8192; }
    else if (j < 20480) { src = Wl2; dst = Wc2; local = j - 16384; }
    else if (j < 24576) { src = Wr2; dst = Wc2 + 16384; local = j - 20480; }
    else return;
    float4 v = ((const float4*)src)[local];
    ushort4 o;
    o.x = f2bf(v.x); o.y = f2bf(v.y); o.z = f2bf(v.z); o.w = f2bf(v.w);
    ((ushort4*)dst)[local] = o;
  }
}

__global__ __launch_bounds__(1024) void scan_kernel(const int* __restrict__ counts,
                                                    int* __restrict__ row_start, int n) {
  __shared__ int wsum[16];
  __shared__ int carry;
  int tid = threadIdx.x;
  int lane = tid & 63, wid = tid >> 6;
  if (tid == 0) { carry = 0; row_start[0] = 0; }
  __syncthreads();
  for (int base = 0; base < n; base += 4096) {
    int i0 = base + tid * 4;
    int4 c = make_int4(0, 0, 0, 0);
    if (i0 + 3 < n) c = *(const int4*)&counts[i0];
    else {
      if (i0 + 0 < n) c.x = counts[i0 + 0];
      if (i0 + 1 < n) c.y = counts[i0 + 1];
      if (i0 + 2 < n) c.z = counts[i0 + 2];
      if (i0 + 3 < n) c.w = counts[i0 + 3];
    }
    int s1 = c.x + c.y, s2 = s1 + c.z, s3 = s2 + c.w;
    int x = s3;
#pragma unroll
    for (int offd = 1; offd < 64; offd <<= 1) {
      int t = __shfl_up(x, offd, 64);
      if (lane >= offd) x += t;
    }
    if (lane == 63) wsum[wid] = x;
    __syncthreads();
    if (wid == 0) {
      int v2 = (lane < 16) ? wsum[lane] : 0;
#pragma unroll
      for (int offd = 1; offd < 16; offd <<= 1) {
        int t = __shfl_up(v2, offd, 64);
        if (lane >= offd) v2 += t;
      }
      if (lane < 16) wsum[lane] = v2;
    }
    __syncthreads();
    int pre = (wid > 0 ? wsum[wid - 1] : 0) + carry + (x - s3);
    if (i0 + 0 < n) row_start[i0 + 1] = pre + c.x;
    if (i0 + 1 < n) row_start[i0 + 2] = pre + s1;
    if (i0 + 2 < n) row_start[i0 + 3] = pre + s2;
    if (i0 + 3 < n) row_start[i0 + 4] = pre + s3;
    __syncthreads();
    if (tid == 0) carry += wsum[15];
    __syncthreads();
  }
}

__global__ void scatter_kernel(const int* __restrict__ ei, int E, int N,
                               const int* __restrict__ row_start,
                               int* __restrict__ cursor, int* __restrict__ csr_src) {
  int e = blockIdx.x * blockDim.x + threadIdx.x;
  int etot = E + N;
  if (e >= etot) return;
  int src, dst;
  if (e < E) { src = ei[e]; dst = ei[E + e]; } else { src = e - E; dst = src; }
  int pos = row_start[dst] + atomicAdd(&cursor[dst], 1);
  csr_src[pos] = src;
}

// ---------------- MFMA GEMM1: C[M,512](bf16) = x[M,128](f32->bf16) @ W^T + bias
// 512-thread blocks: 8 waves share one 64-row A tile (L1 reuse); wave wv -> cols wv*64.
#define MFMA16 __builtin_amdgcn_mfma_f32_16x16x32_bf16
__global__ __launch_bounds__(512) void mfma_gemm1(
    const float* __restrict__ A, const unsigned short* __restrict__ W,
    const float* __restrict__ bl, const float* __restrict__ br,
    unsigned short* __restrict__ C, int M) {
  int lane = threadIdx.x & 63;
  int wv = threadIdx.x >> 6;
  int m0 = blockIdx.x * 64;
  int n0 = wv * 64;
  int lr = lane & 15, lk = (lane >> 4) * 8;
  const float* bp = (n0 < 256) ? bl : br;
  int nb = n0 & 255;

  short8 bfrag[4][4];
#pragma unroll
  for (int nf = 0; nf < 4; ++nf)
#pragma unroll
    for (int ks = 0; ks < 4; ++ks)
      bfrag[nf][ks] = *(const short8*)&W[(size_t)(n0 + nf * 16 + lr) * 128 + ks * 32 + lk];

  f32x4 acc[4][4];
#pragma unroll
  for (int i = 0; i < 4; ++i)
#pragma unroll
    for (int j = 0; j < 4; ++j) acc[i][j] = (f32x4){0.f, 0.f, 0.f, 0.f};

#pragma unroll
  for (int mf = 0; mf < 4; ++mf) {
    int mr = m0 + mf * 16 + lr;
    int mrc = mr < M ? mr : 0;
    short8 afrag[4];
#pragma unroll
    for (int ks = 0; ks < 4; ++ks) {
      const float* ap = &A[(size_t)mrc * 128 + ks * 32 + lk];
      float4 a0 = *(const float4*)ap;
      float4 a1 = *(const float4*)(ap + 4);
      uint4 u;
      u.x = cvtpk_bf16(a0.x, a0.y);
      u.y = cvtpk_bf16(a0.z, a0.w);
      u.z = cvtpk_bf16(a1.x, a1.y);
      u.w = cvtpk_bf16(a1.z, a1.w);
      afrag[ks] = __builtin_bit_cast(short8, u);
    }
#pragma unroll
    for (int ks = 0; ks < 4; ++ks)
#pragma unroll
      for (int nf = 0; nf < 4; ++nf)
        acc[mf][nf] = MFMA16(afrag[ks], bfrag[nf][ks], acc[mf][nf], 0, 0, 0);
  }

  int cr = (lane >> 4) * 4;
#pragma unroll
  for (int mf = 0; mf < 4; ++mf) {
#pragma unroll
    for (int r = 0; r < 4; ++r) {
      int m = m0 + mf * 16 + cr + r;
      if (m < M) {
#pragma unroll
        for (int nf = 0; nf < 4; ++nf) {
          int n = n0 + nf * 16 + lr;
          float v = acc[mf][nf][r] + bp[nb + nf * 16 + lr];
          C[(size_t)m * HD + n] = f2bf(v);
        }
      }
    }
  }
}

// ---------------- MFMA GEMM2: C[M,512](bf16) = h1[M,64](bf16) @ W^T + bias
__global__ __launch_bounds__(512) void mfma_gemm2(
    const unsigned short* __restrict__ A, const unsigned short* __restrict__ W,
    const float* __restrict__ bl, const float* __restrict__ br,
    unsigned short* __restrict__ C, int M) {
  int lane = threadIdx.x & 63;
  int wv = threadIdx.x >> 6;
  int m0 = blockIdx.x * 64;
  int n0 = wv * 64;
  int lr = lane & 15, lk = (lane >> 4) * 8;
  const float* bp = (n0 < 256) ? bl : br;
  int nb = n0 & 255;

  short8 bfrag[4][2];
#pragma unroll
  for (int nf = 0; nf < 4; ++nf)
#pragma unroll
    for (int ks = 0; ks < 2; ++ks)
      bfrag[nf][ks] = *(const short8*)&W[(size_t)(n0 + nf * 16 + lr) * 64 + ks * 32 + lk];

  f32x4 acc[4][4];
#pragma unroll
  for (int i = 0; i < 4; ++i)
#pragma unroll
    for (int j = 0; j < 4; ++j) acc[i][j] = (f32x4){0.f, 0.f, 0.f, 0.f};

#pragma unroll
  for (int mf = 0; mf < 4; ++mf) {
    int mr = m0 + mf * 16 + lr;
    int mrc = mr < M ? mr : 0;
    short8 afrag[2];
#pragma unroll
    for (int ks = 0; ks < 2; ++ks)
      afrag[ks] = *(const short8*)&A[(size_t)mrc * 64 + ks * 32 + lk];
#pragma unroll
    for (int ks = 0; ks < 2; ++ks)
#pragma unroll
      for (int nf = 0; nf < 4; ++nf)
        acc[mf][nf] = MFMA16(afrag[ks], bfrag[nf][ks], acc[mf][nf], 0, 0, 0);
  }

  int cr = (lane >> 4) * 4;
#pragma unroll
  for (int mf = 0; mf < 4; ++mf) {
#pragma unroll
    for (int r = 0; r < 4; ++r) {
      int m = m0 + mf * 16 + cr + r;
      if (m < M) {
#pragma unroll
        for (int nf = 0; nf < 4; ++nf) {
          int n = n0 + nf * 16 + lr;
          float v = acc[mf][nf][r] + bp[nb + nf * 16 + lr];
          C[(size_t)m * HD + n] = f2bf(v);
        }
      }
    }
  }
}

// ---------------- Fused GATv2 per-node aggregate + LN + ELU (+ MLP) ----------------
// One wave per node; lane l owns channels 4l..4l+3; the 4 sixteen-lane rows = 4 heads
// (per-lane ssum IS the per-head denominator — no cross-row reduce on it).
// Indices wave-batched: 1 vector load per 64 edges; per-edge index via readlane
// (SGPR) so the gather address is formed in SALU.
template <bool LAST>
__global__ __launch_bounds__(256) void gat_kernel(
    const unsigned short* __restrict__ xlr,
    const float* __restrict__ att, const float* __restrict__ bias,
    const float* __restrict__ gamma, const float* __restrict__ beta,
    const int* __restrict__ row_start, const int* __restrict__ csr_src,
    const float* __restrict__ Wh1, const float* __restrict__ bh1,
    const float* __restrict__ Wh2, const float* __restrict__ bh2,
    void* __restrict__ outp, int N) {
  __shared__ float sh[4][96];
  int wid = threadIdx.x >> 6;
  int lane = threadIdx.x & 63;
  int v = blockIdx.x * 4 + wid;
  if (v >= N) return;
  int c0 = 4 * lane;
  int cc = 4 * (lane & 15);

  uint2 ur = *(const uint2*)&xlr[(size_t)v * HD + 256 + c0];
  float xr0 = ubits(ur.x << 16), xr1 = ubits(ur.x & 0xffff0000u);
  float xr2 = ubits(ur.y << 16), xr3 = ubits(ur.y & 0xffff0000u);
  float4 at4 = *(const float4*)&att[c0];

  float sA = 0.f, sB = 0.f;
  float aA0 = 0.f, aA1 = 0.f, aA2 = 0.f, aA3 = 0.f;
  float aB0 = 0.f, aB1 = 0.f, aB2 = 0.f, aB3 = 0.f;

  int rs = __builtin_amdgcn_readfirstlane(row_start[v]);
  int re = __builtin_amdgcn_readfirstlane(row_start[v + 1]);

  auto edge = [&](uint2 u, bool valid, float& ss, float& a0, float& a1,
                  float& a2, float& a3) {
    float x0 = ubits(u.x << 16), x1 = ubits(u.x & 0xffff0000u);
    float x2 = ubits(u.y << 16), x3 = ubits(u.y & 0xffff0000u);
    float t0 = x0 + xr0, t1 = x1 + xr1, t2 = x2 + xr2, t3 = x3 + xr3;
    // sum(att*leaky(t)) = 0.6*sum(att*t) + 0.4*sum(att*|t|)
    float p6 = t0 * at4.x;
    p6 = fmaf(t1, at4.y, p6);
    p6 = fmaf(t2, at4.z, p6);
    p6 = fmaf(t3, at4.w, p6);
    float p4 = fabsf(t0) * at4.x;
    p4 = fmaf(fabsf(t1), at4.y, p4);
    p4 = fmaf(fabsf(t2), at4.z, p4);
    p4 = fmaf(fabsf(t3), at4.w, p4);
    float sc = fmaf(0.4f, p4, 0.6f * p6);
    sc = dpp_add<0x121>(sc);  // row_ror:1
    sc = dpp_add<0x122>(sc);  // row_ror:2
    sc = dpp_add<0x124>(sc);  // row_ror:4
    sc = dpp_add<0x128>(sc);  // row_ror:8 -> 16-lane (per-head) sum
    float p = __expf(sc);  // scores O(1): softmax shift not needed
    p = valid ? p : 0.f;
    ss += p;
    a0 = fmaf(p, t0, a0);  // accumulate p*t; undo +xr after loop
    a1 = fmaf(p, t1, a1);
    a2 = fmaf(p, t2, a2);
    a3 = fmaf(p, t3, a3);
  };

  for (int b0 = rs; b0 < re; b0 += 64) {
    int li = b0 + lane;
    int idxv = csr_src[li < re ? li : re - 1];  // 64 indices, 1 load
    int cnt = re - b0;
    if (cnt > 64) cnt = 64;

    auto fetchk = [&](int k) -> uint2 {  // k uniform
      int kk = k < cnt ? k : cnt - 1;
      int s = __builtin_amdgcn_readlane(idxv, kk);  // SGPR index
      return *(const uint2*)&xlr[(size_t)s * HD + c0];  // SALU-based address
    };

    uint2 A0, A1, A2, A3, B0, B1, B2, B3;
    A0 = fetchk(0); A1 = fetchk(1); A2 = fetchk(2); A3 = fetchk(3);
    int b = 0;
    while (true) {
      int nb = b + 4;
      if (nb < cnt) { B0 = fetchk(nb); B1 = fetchk(nb + 1); B2 = fetchk(nb + 2); B3 = fetchk(nb + 3); }
      edge(A0, true, sA, aA0, aA1, aA2, aA3);
      edge(A1, b + 1 < cnt, sB, aB0, aB1, aB2, aB3);
      edge(A2, b + 2 < cnt, sA, aA0, aA1, aA2, aA3);
      edge(A3, b + 3 < cnt, sB, aB0, aB1, aB2, aB3);
      b = nb;
      if (b >= cnt) break;
      nb = b + 4;
      if (nb < cnt) { A0 = fetchk(nb); A1 = fetchk(nb + 1); A2 = fetchk(nb + 2); A3 = fetchk(nb + 3); }
      edge(B0, true, sA, aA0, aA1, aA2, aA3);
      edge(B1, b + 1 < cnt, sB, aB0, aB1, aB2, aB3);
      edge(B2, b + 2 < cnt, sA, aA0, aA1, aA2, aA3);
      edge(B3, b + 3 < cnt, sB, aB0, aB1, aB2, aB3);
      b = nb;
      if (b >= cnt) break;
    }
  }

  // per-lane (= per-head) softmax denominator; no cross-row reduction here
  float inv = 1.f / (sA + sB);  // self-loop guarantees > 0

  float am[4] = {aA0 + aB0, aA1 + aB1, aA2 + aB2, aA3 + aB3};
  float xrv[4] = {xr0, xr1, xr2, xr3};
  float hv[4];
#pragma unroll
  for (int j = 0; j < 4; ++j) {
    float a = fmaf(am[j], inv, -xrv[j]);  // normalize per-head, undo +xr
    a += __shfl_xor(a, 16);               // then sum the 4 heads
    a += __shfl_xor(a, 32);
    hv[j] = a;
  }
  float4 bias4 = *(const float4*)&bias[cc];
  hv[0] = 0.25f * hv[0] + bias4.x;
  hv[1] = 0.25f * hv[1] + bias4.y;
  hv[2] = 0.25f * hv[2] + bias4.z;
  hv[3] = 0.25f * hv[3] + bias4.w;
  float psum = hv[0] + hv[1] + hv[2] + hv[3];
  float psq = hv[0] * hv[0] + hv[1] * hv[1] + hv[2] * hv[2] + hv[3] * hv[3];
#pragma unroll
  for (int o = 1; o < 16; o <<= 1) {
    psum += __shfl_xor(psum, o);
    psq += __shfl_xor(psq, o);
  }
  float mean = psum * (1.f / 64.f);
  float var = psq * (1.f / 64.f) - mean * mean;
  float rstd = rsqrtf(var + 1e-5f);
  float4 g4 = *(const float4*)&gamma[cc];
  float4 be4 = *(const float4*)&beta[cc];
  float y[4];
  y[0] = (hv[0] - mean) * rstd * g4.x + be4.x;
  y[1] = (hv[1] - mean) * rstd * g4.y + be4.y;
  y[2] = (hv[2] - mean) * rstd * g4.z + be4.z;
  y[3] = (hv[3] - mean) * rstd * g4.w + be4.w;
#pragma unroll
  for (int j = 0; j < 4; ++j) y[j] = y[j] > 0.f ? y[j] : expm1f(y[j]);

  if (!LAST) {
    if (lane < 16) {
      ushort4 o;
      o.x = f2bf(y[0]); o.y = f2bf(y[1]); o.z = f2bf(y[2]); o.w = f2bf(y[3]);
      *(ushort4*)&((unsigned short*)outp)[(size_t)v * HIDC + cc] = o;
    }
  } else {
    float* out = (float*)outp;
    if (lane < 16) {
      sh[wid][cc + 0] = y[0]; sh[wid][cc + 1] = y[1];
      sh[wid][cc + 2] = y[2]; sh[wid][cc + 3] = y[3];
    }
    if (lane < 32) {  // same-wave LDS ordering; waves independent
      float a = bh1[lane];
      const float* wrow = &Wh1[lane * 64];
#pragma unroll 8
      for (int k = 0; k < 64; ++k) a += sh[wid][k] * wrow[k];
      sh[wid][64 + lane] = fmaxf(a, 0.f);
    }
    if (lane < 2) {
      float o = bh2[lane];
      const float* wrow = &Wh2[lane * 32];
#pragma unroll 8
      for (int k = 0; k < 32; ++k) o += sh[wid][64 + k] * wrow[k];
      out[(size_t)v * 2 + lane] = o;
    }
  }
}

// ---------------- launch ----------------
extern "C" void kernel_launch(void* const* d_in, const int* in_sizes, int n_in,
                              void* d_out, int out_size, void* d_ws, size_t ws_size,
                              hipStream_t stream) {
  const float* x = (const float*)d_in[0];
  const int* ei = (const int*)d_in[1];
  const float* Wl1 = (const float*)d_in[2]; const float* bl1 = (const float*)d_in[3];
  const float* Wr1 = (const float*)d_in[4]; const float* br1 = (const float*)d_in[5];
  const float* att1 = (const float*)d_in[6]; const float* bias1 = (const float*)d_in[7];
  const float* Wl2 = (const float*)d_in[8]; const float* bl2 = (const float*)d_in[9];
  const float* Wr2 = (const float*)d_in[10]; const float* br2 = (const float*)d_in[11];
  const float* att2 = (const float*)d_in[12]; const float* bias2 = (const float*)d_in[13];
  const float* g1 = (const float*)d_in[14]; const float* be1 = (const float*)d_in[15];
  const float* g2 = (const float*)d_in[16]; const float* be2 = (const float*)d_in[17];
  const float* Wh1 = (const float*)d_in[18]; const float* bh1 = (const float*)d_in[19];
  const float* Wh2 = (const float*)d_in[20]; const float* bh2 = (const float*)d_in[21];
  float* out = (float*)d_out;

  int N = in_sizes[0] / 128;
  int E = in_sizes[1] / 2;
  int ET = E + N;

  char* ws = (char*)d_ws;
  size_t off = 0;
  auto alloc = [&](size_t bytes) {
    void* p = ws + off;
    off += (bytes + 255) & ~(size_t)255;
    return p;
  };
  unsigned short* xlr = (unsigned short*)alloc((size_t)N * HD * 2);
  unsigned short* h1b = (unsigned short*)alloc((size_t)N * HIDC * 2);
  unsigned short* Wc1 = (unsigned short*)alloc((size_t)512 * 128 * 2);
  unsigned short* Wc2 = (unsigned short*)alloc((size_t)512 * 64 * 2);
  int* row_start = (int*)alloc((size_t)(N + 1) * 4);
  int* counts = (int*)alloc((size_t)N * 4);
  int* cursor = (int*)alloc((size_t)N * 4);
  int* csr = (int*)alloc((size_t)ET * 4);

  hipMemsetAsync(counts, 0, (size_t)N * 4, stream);
  hipMemsetAsync(cursor, 0, (size_t)N * 4, stream);

  int eb = (ET + 255) / 256;
  prep_kernel<<<eb + 96, 256, 0, stream>>>(ei, E, N, eb, counts,
                                           Wl1, Wr1, Wl2, Wr2, Wc1, Wc2);
  scan_kernel<<<1, 1024, 0, stream>>>(counts, row_start, N);
  scatter_kernel<<<eb, 256, 0, stream>>>(ei, E, N, row_start, cursor, csr);

  int gx = (N + 63) / 64;
  mfma_gemm1<<<gx, 512, 0, stream>>>(x, Wc1, bl1, br1, xlr, N);

  int gb = (N + 3) / 4;
  gat_kernel<false><<<gb, 256, 0, stream>>>(xlr, att1, bias1, g1, be1,
                                            row_start, csr, nullptr, nullptr,
                                            nullptr, nullptr, h1b, N);

  mfma_gemm2<<<gx, 512, 0, stream>>>(h1b, Wc2, bl2, br2, xlr, N);

  gat_kernel<true><<<gb, 256, 0, stream>>>(xlr, att2, bias2, g2, be2,
                                           row_start, csr, Wh1, bh1, Wh2, bh2,
                                           out, N);
}

// Round 7
// 374.105 us; speedup vs baseline: 1.0238x; 1.0238x over previous
//
#include <hip/hip_runtime.h>
#include <math.h>

#define HIDC 64
#define HD 512  // combined xl|xr channels per node (bf16)

typedef unsigned int uint32;
using short8 = __attribute__((ext_vector_type(8))) short;
using f32x4 = __attribute__((ext_vector_type(4))) float;
using f32x2 = __attribute__((ext_vector_type(2))) float;

__device__ inline float ubits(uint32 u) { return __builtin_bit_cast(float, u); }
__device__ inline unsigned short f2bf(float x) {
  uint32 u = __builtin_bit_cast(uint32, x);
  return (unsigned short)((u + 0x7fffu + ((u >> 16) & 1u)) >> 16);
}

// CDNA packed-FP32: one issue = 2 lanes' worth of f32 math per lane
__device__ inline f32x2 pk_add(f32x2 a, f32x2 b) {
  f32x2 d; asm("v_pk_add_f32 %0, %1, %2" : "=v"(d) : "v"(a), "v"(b)); return d;
}
__device__ inline f32x2 pk_mul(f32x2 a, f32x2 b) {
  f32x2 d; asm("v_pk_mul_f32 %0, %1, %2" : "=v"(d) : "v"(a), "v"(b)); return d;
}
__device__ inline f32x2 pk_fma(f32x2 a, f32x2 b, f32x2 c) {
  f32x2 d; asm("v_pk_fma_f32 %0, %1, %2, %3" : "=v"(d) : "v"(a), "v"(b), "v"(c)); return d;
}
__device__ inline f32x2 max2(f32x2 a, f32x2 b) {
  f32x2 d; d.x = fmaxf(a.x, b.x); d.y = fmaxf(a.y, b.y); return d;
}

template <int CTRL>
__device__ inline float dpp_add(float x) {
  int xi = __builtin_bit_cast(int, x);
  int s = __builtin_amdgcn_update_dpp(0, xi, CTRL, 0xf, 0xf, true);
  return x + __builtin_bit_cast(float, s);
}

// ---------------- CSR build ----------------
__global__ void count_kernel(const int* __restrict__ ei, int E, int N,
                             int* __restrict__ counts) {
  int e = blockIdx.x * blockDim.x + threadIdx.x;
  int etot = E + N;
  if (e >= etot) return;
  int dst = (e < E) ? ei[E + e] : (e - E);
  atomicAdd(&counts[dst], 1);
}

__global__ __launch_bounds__(1024) void scan_kernel(const int* __restrict__ counts,
                                                    int* __restrict__ row_start, int n) {
  __shared__ int wsum[16];
  __shared__ int carry;
  int tid = threadIdx.x;
  int lane = tid & 63, wid = tid >> 6;
  if (tid == 0) { carry = 0; row_start[0] = 0; }
  __syncthreads();
  for (int base = 0; base < n; base += 4096) {
    int i0 = base + tid * 4;
    int4 c = make_int4(0, 0, 0, 0);
    if (i0 + 3 < n) c = *(const int4*)&counts[i0];
    else {
      if (i0 + 0 < n) c.x = counts[i0 + 0];
      if (i0 + 1 < n) c.y = counts[i0 + 1];
      if (i0 + 2 < n) c.z = counts[i0 + 2];
      if (i0 + 3 < n) c.w = counts[i0 + 3];
    }
    int s1 = c.x + c.y, s2 = s1 + c.z, s3 = s2 + c.w;
    int x = s3;
#pragma unroll
    for (int offd = 1; offd < 64; offd <<= 1) {
      int t = __shfl_up(x, offd, 64);
      if (lane >= offd) x += t;
    }
    if (lane == 63) wsum[wid] = x;
    __syncthreads();
    if (wid == 0) {
      int v2 = (lane < 16) ? wsum[lane] : 0;
#pragma unroll
      for (int offd = 1; offd < 16; offd <<= 1) {
        int t = __shfl_up(v2, offd, 64);
        if (lane >= offd) v2 += t;
      }
      if (lane < 16) wsum[lane] = v2;
    }
    __syncthreads();
    int pre = (wid > 0 ? wsum[wid - 1] : 0) + carry + (x - s3);
    if (i0 + 0 < n) row_start[i0 + 1] = pre + c.x;
    if (i0 + 1 < n) row_start[i0 + 2] = pre + s1;
    if (i0 + 2 < n) row_start[i0 + 3] = pre + s2;
    if (i0 + 3 < n) row_start[i0 + 4] = pre + s3;
    __syncthreads();
    if (tid == 0) carry += wsum[15];
    __syncthreads();
  }
}

__global__ void scatter_kernel(const int* __restrict__ ei, int E, int N,
                               const int* __restrict__ row_start,
                               int* __restrict__ cursor, int* __restrict__ csr_src) {
  int e = blockIdx.x * blockDim.x + threadIdx.x;
  int etot = E + N;
  if (e >= etot) return;
  int src, dst;
  if (e < E) { src = ei[e]; dst = ei[E + e]; } else { src = e - E; dst = src; }
  int pos = row_start[dst] + atomicAdd(&cursor[dst], 1);
  csr_src[pos] = src;
}

// ---------------- fused fp32 -> bf16 pack for x + all 4 weights ----------------
__global__ void pack_all(const float* __restrict__ x,
                         const float* __restrict__ Wl1, const float* __restrict__ Wr1,
                         const float* __restrict__ Wl2, const float* __restrict__ Wr2,
                         unsigned short* __restrict__ xb, unsigned short* __restrict__ Wc1,
                         unsigned short* __restrict__ Wc2, int n4x) {
  int i = blockIdx.x * blockDim.x + threadIdx.x;
  const float* src;
  unsigned short* dst;
  int local;
  if (i < n4x) { src = x; dst = xb; local = i; }
  else {
    int j = i - n4x;
    if (j < 8192) { src = Wl1; dst = Wc1; local = j; }
    else if (j < 16384) { src = Wr1; dst = Wc1 + 32768; local = j - 8192; }
    else if (j < 20480) { src = Wl2; dst = Wc2; local = j - 16384; }
    else if (j < 24576) { src = Wr2; dst = Wc2 + 16384; local = j - 20480; }
    else return;
  }
  float4 v = ((const float4*)src)[local];
  ushort4 o;
  o.x = f2bf(v.x); o.y = f2bf(v.y); o.z = f2bf(v.z); o.w = f2bf(v.w);
  ((ushort4*)dst)[local] = o;
}

// ---------------- MFMA GEMM: C[M,512](bf16) = A[M,K](bf16) @ W[512,K](bf16)^T + bias
// Block = 4 waves sharing ONE 64-row A tile (L1 reuse); wave wv covers n0=y*256+wv*64.
#define MFMA16 __builtin_amdgcn_mfma_f32_16x16x32_bf16
template <int K>
__global__ __launch_bounds__(256, 2) void mfma_gemm(
    const unsigned short* __restrict__ A, const unsigned short* __restrict__ W,
    const float* __restrict__ bl, const float* __restrict__ br,
    unsigned short* __restrict__ C, int M) {
  int lane = threadIdx.x & 63;
  int wv = threadIdx.x >> 6;
  int m0 = blockIdx.x * 64;
  int n0 = blockIdx.y * 256 + wv * 64;
  int lr = lane & 15, lk = (lane >> 4) * 8;
  const float* bp = (n0 < 256) ? bl : br;
  int nb = n0 & 255;

  short8 bfrag[4][K / 32];
#pragma unroll
  for (int nf = 0; nf < 4; ++nf)
#pragma unroll
    for (int ks = 0; ks < K / 32; ++ks)
      bfrag[nf][ks] = *(const short8*)&W[(size_t)(n0 + nf * 16 + lr) * K + ks * 32 + lk];

  f32x4 acc[4][4];
#pragma unroll
  for (int i = 0; i < 4; ++i)
#pragma unroll
    for (int j = 0; j < 4; ++j) acc[i][j] = (f32x4){0.f, 0.f, 0.f, 0.f};

#pragma unroll
  for (int mf = 0; mf < 4; ++mf) {
    int mr = m0 + mf * 16 + lr;
    int mrc = mr < M ? mr : 0;
    short8 afrag[K / 32];
#pragma unroll
    for (int ks = 0; ks < K / 32; ++ks)
      afrag[ks] = *(const short8*)&A[(size_t)mrc * K + ks * 32 + lk];
#pragma unroll
    for (int ks = 0; ks < K / 32; ++ks)
#pragma unroll
      for (int nf = 0; nf < 4; ++nf)
        acc[mf][nf] = MFMA16(afrag[ks], bfrag[nf][ks], acc[mf][nf], 0, 0, 0);
  }

  int cr = (lane >> 4) * 4;
#pragma unroll
  for (int mf = 0; mf < 4; ++mf) {
#pragma unroll
    for (int r = 0; r < 4; ++r) {
      int m = m0 + mf * 16 + cr + r;
      if (m < M) {
#pragma unroll
        for (int nf = 0; nf < 4; ++nf) {
          int n = n0 + nf * 16 + lr;
          float v = acc[mf][nf][r] + bp[nb + nf * 16 + lr];
          C[(size_t)m * HD + n] = f2bf(v);
        }
      }
    }
  }
}

// ---------------- Fused GATv2 per-node aggregate + LN + ELU (+ MLP) ----------------
// One wave per node; lane l owns channels 4l..4l+3; the 4 sixteen-lane rows = 4 heads
// (per-lane ssum IS the per-head denominator — no cross-row reduce on it).
// Inner math packs TWO EDGES per f32x2 register pair: one v_pk_* op handles a
// channel for both edges; the dot-reduce yields {score_a, score_b} directly.
// exp(score) = exp2(score*log2e) with log2e folded into att (atB).
template <bool LAST>
__global__ __launch_bounds__(256) void gat_kernel(
    const unsigned short* __restrict__ xlr,
    const float* __restrict__ att, const float* __restrict__ bias,
    const float* __restrict__ gamma, const float* __restrict__ beta,
    const int* __restrict__ row_start, const int* __restrict__ csr_src,
    const float* __restrict__ Wh1, const float* __restrict__ bh1,
    const float* __restrict__ Wh2, const float* __restrict__ bh2,
    void* __restrict__ outp, int N) {
  __shared__ float sh[4][96];
  int wid = threadIdx.x >> 6;
  int lane = threadIdx.x & 63;
  int v = blockIdx.x * 4 + wid;
  if (v >= N) return;
  int c0 = 4 * lane;
  int cc = 4 * (lane & 15);

  uint2 ur = *(const uint2*)&xlr[(size_t)v * HD + 256 + c0];
  float xr0 = ubits(ur.x << 16), xr1 = ubits(ur.x & 0xffff0000u);
  float xr2 = ubits(ur.y << 16), xr3 = ubits(ur.y & 0xffff0000u);
  float4 at4 = *(const float4*)&att[c0];
  const float L2E = 1.4426950408889634f;

  // broadcast pairs (same value both halves)
  f32x2 xrB0 = {xr0, xr0}, xrB1 = {xr1, xr1}, xrB2 = {xr2, xr2}, xrB3 = {xr3, xr3};
  f32x2 atB0 = {at4.x * L2E, at4.x * L2E}, atB1 = {at4.y * L2E, at4.y * L2E};
  f32x2 atB2 = {at4.z * L2E, at4.z * L2E}, atB3 = {at4.w * L2E, at4.w * L2E};
  f32x2 c02 = {0.2f, 0.2f};

  f32x2 ssumP = {0.f, 0.f};
  f32x2 accP0 = {0.f, 0.f}, accP1 = {0.f, 0.f}, accP2 = {0.f, 0.f}, accP3 = {0.f, 0.f};

  int rs = __builtin_amdgcn_readfirstlane(row_start[v]);
  int re = __builtin_amdgcn_readfirstlane(row_start[v + 1]);

  auto fetchi = [&](int i) -> uint2 {
    int ic = i < re ? i : re - 1;  // scalar clamp; masked at accumulate
    int s = csr_src[ic];
    return *(const uint2*)&xlr[(size_t)s * HD + c0];
  };

  // two edges a,b at once; each f32x2 = {edge_a, edge_b} for one channel
  auto pair2 = [&](uint2 ua, uint2 ub, bool v0, bool v1) {
    f32x2 P0 = {ubits(ua.x << 16), ubits(ub.x << 16)};
    f32x2 P1 = {ubits(ua.x & 0xffff0000u), ubits(ub.x & 0xffff0000u)};
    f32x2 P2 = {ubits(ua.y << 16), ubits(ub.y << 16)};
    f32x2 P3 = {ubits(ua.y & 0xffff0000u), ubits(ub.y & 0xffff0000u)};
    f32x2 t0 = pk_add(P0, xrB0);
    f32x2 t1 = pk_add(P1, xrB1);
    f32x2 t2 = pk_add(P2, xrB2);
    f32x2 t3 = pk_add(P3, xrB3);
    f32x2 l0 = max2(t0, pk_mul(t0, c02));  // leaky_relu, slope 0.2
    f32x2 l1 = max2(t1, pk_mul(t1, c02));
    f32x2 l2 = max2(t2, pk_mul(t2, c02));
    f32x2 l3 = max2(t3, pk_mul(t3, c02));
    f32x2 sc = pk_mul(l0, atB0);
    sc = pk_fma(l1, atB1, sc);
    sc = pk_fma(l2, atB2, sc);
    sc = pk_fma(l3, atB3, sc);  // {score_a, score_b} * log2e (lane partial)
    float sx = sc.x, sy = sc.y;
    sx = dpp_add<0x121>(sx); sx = dpp_add<0x122>(sx);
    sx = dpp_add<0x124>(sx); sx = dpp_add<0x128>(sx);  // 16-lane head sum
    sy = dpp_add<0x121>(sy); sy = dpp_add<0x122>(sy);
    sy = dpp_add<0x124>(sy); sy = dpp_add<0x128>(sy);
    float px = exp2f(sx);  // scores O(1): softmax shift not needed
    float py = exp2f(sy);
    px = v0 ? px : 0.f;
    py = v1 ? py : 0.f;
    f32x2 p = {px, py};
    ssumP = pk_add(ssumP, p);
    accP0 = pk_fma(p, t0, accP0);  // accumulate p*t; undo +xr after loop
    accP1 = pk_fma(p, t1, accP1);
    accP2 = pk_fma(p, t2, accP2);
    accP3 = pk_fma(p, t3, accP3);
  };

  uint2 A0, A1, A2, A3, B0, B1, B2, B3;
  A0 = fetchi(rs); A1 = fetchi(rs + 1); A2 = fetchi(rs + 2); A3 = fetchi(rs + 3);
  int b = rs;
  while (true) {
    int nb = b + 4;
    if (nb < re) { B0 = fetchi(nb); B1 = fetchi(nb + 1); B2 = fetchi(nb + 2); B3 = fetchi(nb + 3); }
    pair2(A0, A1, true, b + 1 < re);
    pair2(A2, A3, b + 2 < re, b + 3 < re);
    b = nb;
    if (b >= re) break;
    nb = b + 4;
    if (nb < re) { A0 = fetchi(nb); A1 = fetchi(nb + 1); A2 = fetchi(nb + 2); A3 = fetchi(nb + 3); }
    pair2(B0, B1, true, b + 1 < re);
    pair2(B2, B3, b + 2 < re, b + 3 < re);
    b = nb;
    if (b >= re) break;
  }

  // per-lane (= per-head) softmax denominator
  float inv = 1.f / (ssumP.x + ssumP.y);  // self-loop guarantees > 0

  float am[4] = {accP0.x + accP0.y, accP1.x + accP1.y,
                 accP2.x + accP2.y, accP3.x + accP3.y};
  float xrv[4] = {xr0, xr1, xr2, xr3};
  float hv[4];
#pragma unroll
  for (int j = 0; j < 4; ++j) {
    float a = fmaf(am[j], inv, -xrv[j]);  // normalize per-head, undo +xr
    a += __shfl_xor(a, 16);               // then sum the 4 heads
    a += __shfl_xor(a, 32);
    hv[j] = a;
  }
  float4 bias4 = *(const float4*)&bias[cc];
  hv[0] = 0.25f * hv[0] + bias4.x;
  hv[1] = 0.25f * hv[1] + bias4.y;
  hv[2] = 0.25f * hv[2] + bias4.z;
  hv[3] = 0.25f * hv[3] + bias4.w;
  float psum = hv[0] + hv[1] + hv[2] + hv[3];
  float psq = hv[0] * hv[0] + hv[1] * hv[1] + hv[2] * hv[2] + hv[3] * hv[3];
#pragma unroll
  for (int o = 1; o < 16; o <<= 1) {
    psum += __shfl_xor(psum, o);
    psq += __shfl_xor(psq, o);
  }
  float mean = psum * (1.f / 64.f);
  float var = psq * (1.f / 64.f) - mean * mean;
  float rstd = rsqrtf(var + 1e-5f);
  float4 g4 = *(const float4*)&gamma[cc];
  float4 be4 = *(const float4*)&beta[cc];
  float y[4];
  y[0] = (hv[0] - mean) * rstd * g4.x + be4.x;
  y[1] = (hv[1] - mean) * rstd * g4.y + be4.y;
  y[2] = (hv[2] - mean) * rstd * g4.z + be4.z;
  y[3] = (hv[3] - mean) * rstd * g4.w + be4.w;
#pragma unroll
  for (int j = 0; j < 4; ++j) y[j] = y[j] > 0.f ? y[j] : expm1f(y[j]);

  if (!LAST) {
    if (lane < 16) {
      ushort4 o;
      o.x = f2bf(y[0]); o.y = f2bf(y[1]); o.z = f2bf(y[2]); o.w = f2bf(y[3]);
      *(ushort4*)&((unsigned short*)outp)[(size_t)v * HIDC + cc] = o;
    }
  } else {
    float* out = (float*)outp;
    if (lane < 16) {
      sh[wid][cc + 0] = y[0]; sh[wid][cc + 1] = y[1];
      sh[wid][cc + 2] = y[2]; sh[wid][cc + 3] = y[3];
    }
    if (lane < 32) {  // same-wave LDS ordering; waves independent
      float a = bh1[lane];
      const float* wrow = &Wh1[lane * 64];
#pragma unroll 8
      for (int k = 0; k < 64; ++k) a += sh[wid][k] * wrow[k];
      sh[wid][64 + lane] = fmaxf(a, 0.f);
    }
    if (lane < 2) {
      float o = bh2[lane];
      const float* wrow = &Wh2[lane * 32];
#pragma unroll 8
      for (int k = 0; k < 32; ++k) o += sh[wid][64 + k] * wrow[k];
      out[(size_t)v * 2 + lane] = o;
    }
  }
}

// ---------------- launch ----------------
extern "C" void kernel_launch(void* const* d_in, const int* in_sizes, int n_in,
                              void* d_out, int out_size, void* d_ws, size_t ws_size,
                              hipStream_t stream) {
  const float* x = (const float*)d_in[0];
  const int* ei = (const int*)d_in[1];
  const float* Wl1 = (const float*)d_in[2]; const float* bl1 = (const float*)d_in[3];
  const float* Wr1 = (const float*)d_in[4]; const float* br1 = (const float*)d_in[5];
  const float* att1 = (const float*)d_in[6]; const float* bias1 = (const float*)d_in[7];
  const float* Wl2 = (const float*)d_in[8]; const float* bl2 = (const float*)d_in[9];
  const float* Wr2 = (const float*)d_in[10]; const float* br2 = (const float*)d_in[11];
  const float* att2 = (const float*)d_in[12]; const float* bias2 = (const float*)d_in[13];
  const float* g1 = (const float*)d_in[14]; const float* be1 = (const float*)d_in[15];
  const float* g2 = (const float*)d_in[16]; const float* be2 = (const float*)d_in[17];
  const float* Wh1 = (const float*)d_in[18]; const float* bh1 = (const float*)d_in[19];
  const float* Wh2 = (const float*)d_in[20]; const float* bh2 = (const float*)d_in[21];
  float* out = (float*)d_out;

  int N = in_sizes[0] / 128;
  int E = in_sizes[1] / 2;
  int ET = E + N;

  char* ws = (char*)d_ws;
  size_t off = 0;
  auto alloc = [&](size_t bytes) {
    void* p = ws + off;
    off += (bytes + 255) & ~(size_t)255;
    return p;
  };
  unsigned short* xlr = (unsigned short*)alloc((size_t)N * HD * 2);
  unsigned short* xb  = (unsigned short*)alloc((size_t)N * 128 * 2);
  unsigned short* h1b = (unsigned short*)alloc((size_t)N * HIDC * 2);
  unsigned short* Wc1 = (unsigned short*)alloc((size_t)512 * 128 * 2);
  unsigned short* Wc2 = (unsigned short*)alloc((size_t)512 * 64 * 2);
  int* row_start = (int*)alloc((size_t)(N + 1) * 4);
  int* counts = (int*)alloc((size_t)N * 4);
  int* cursor = (int*)alloc((size_t)N * 4);
  int* csr = (int*)alloc((size_t)ET * 4);

  hipMemsetAsync(counts, 0, (size_t)N * 4, stream);
  hipMemsetAsync(cursor, 0, (size_t)N * 4, stream);

  int eb = (ET + 255) / 256;
  count_kernel<<<eb, 256, 0, stream>>>(ei, E, N, counts);
  scan_kernel<<<1, 1024, 0, stream>>>(counts, row_start, N);
  scatter_kernel<<<eb, 256, 0, stream>>>(ei, E, N, row_start, cursor, csr);

  int n4x = N * 128 / 4;
  int tot4 = n4x + 24576;
  pack_all<<<(tot4 + 255) / 256, 256, 0, stream>>>(x, Wl1, Wr1, Wl2, Wr2,
                                                   xb, Wc1, Wc2, n4x);

  dim3 gg((N + 63) / 64, 2);
  mfma_gemm<128><<<gg, 256, 0, stream>>>(xb, Wc1, bl1, br1, xlr, N);

  int gb = (N + 3) / 4;
  gat_kernel<false><<<gb, 256, 0, stream>>>(xlr, att1, bias1, g1, be1,
                                            row_start, csr, nullptr, nullptr,
                                            nullptr, nullptr, h1b, N);

  mfma_gemm<64><<<gg, 256, 0, stream>>>(h1b, Wc2, bl2, br2, xlr, N);

  gat_kernel<true><<<gb, 256, 0, stream>>>(xlr, att2, bias2, g2, be2,
                                           row_start, csr, Wh1, bh1, Wh2, bh2,
                                           out, N);
}

// Round 8
// 355.646 us; speedup vs baseline: 1.0770x; 1.0519x over previous
//
#include <hip/hip_runtime.h>
#include <math.h>

#define HIDC 64
#define HD 512  // combined xl|xr channels per node (bf16)

typedef unsigned int uint32;
using short8 = __attribute__((ext_vector_type(8))) short;
using f32x4 = __attribute__((ext_vector_type(4))) float;

__device__ inline float ubits(uint32 u) { return __builtin_bit_cast(float, u); }
__device__ inline unsigned short f2bf(float x) {
  uint32 u = __builtin_bit_cast(uint32, x);
  return (unsigned short)((u + 0x7fffu + ((u >> 16) & 1u)) >> 16);
}

template <int CTRL>
__device__ inline float dpp_add(float x) {
  int xi = __builtin_bit_cast(int, x);
  int s = __builtin_amdgcn_update_dpp(0, xi, CTRL, 0xf, 0xf, true);
  return x + __builtin_bit_cast(float, s);
}

// ---------------- CSR build ----------------
__global__ void count_kernel(const int* __restrict__ ei, int E, int N,
                             int* __restrict__ counts) {
  int e = blockIdx.x * blockDim.x + threadIdx.x;
  int etot = E + N;
  if (e >= etot) return;
  int dst = (e < E) ? ei[E + e] : (e - E);
  atomicAdd(&counts[dst], 1);
}

__global__ __launch_bounds__(1024) void scan_kernel(const int* __restrict__ counts,
                                                    int* __restrict__ row_start, int n) {
  __shared__ int wsum[16];
  __shared__ int carry;
  int tid = threadIdx.x;
  int lane = tid & 63, wid = tid >> 6;
  if (tid == 0) { carry = 0; row_start[0] = 0; }
  __syncthreads();
  for (int base = 0; base < n; base += 4096) {
    int i0 = base + tid * 4;
    int4 c = make_int4(0, 0, 0, 0);
    if (i0 + 3 < n) c = *(const int4*)&counts[i0];
    else {
      if (i0 + 0 < n) c.x = counts[i0 + 0];
      if (i0 + 1 < n) c.y = counts[i0 + 1];
      if (i0 + 2 < n) c.z = counts[i0 + 2];
      if (i0 + 3 < n) c.w = counts[i0 + 3];
    }
    int s1 = c.x + c.y, s2 = s1 + c.z, s3 = s2 + c.w;
    int x = s3;
#pragma unroll
    for (int offd = 1; offd < 64; offd <<= 1) {
      int t = __shfl_up(x, offd, 64);
      if (lane >= offd) x += t;
    }
    if (lane == 63) wsum[wid] = x;
    __syncthreads();
    if (wid == 0) {
      int v2 = (lane < 16) ? wsum[lane] : 0;
#pragma unroll
      for (int offd = 1; offd < 16; offd <<= 1) {
        int t = __shfl_up(v2, offd, 64);
        if (lane >= offd) v2 += t;
      }
      if (lane < 16) wsum[lane] = v2;
    }
    __syncthreads();
    int pre = (wid > 0 ? wsum[wid - 1] : 0) + carry + (x - s3);
    if (i0 + 0 < n) row_start[i0 + 1] = pre + c.x;
    if (i0 + 1 < n) row_start[i0 + 2] = pre + s1;
    if (i0 + 2 < n) row_start[i0 + 3] = pre + s2;
    if (i0 + 3 < n) row_start[i0 + 4] = pre + s3;
    __syncthreads();
    if (tid == 0) carry += wsum[15];
    __syncthreads();
  }
}

__global__ void scatter_kernel(const int* __restrict__ ei, int E, int N,
                               const int* __restrict__ row_start,
                               int* __restrict__ cursor, int* __restrict__ csr_src) {
  int e = blockIdx.x * blockDim.x + threadIdx.x;
  int etot = E + N;
  if (e >= etot) return;
  int src, dst;
  if (e < E) { src = ei[e]; dst = ei[E + e]; } else { src = e - E; dst = src; }
  int pos = row_start[dst] + atomicAdd(&cursor[dst], 1);
  csr_src[pos] = src;
}

// ---------------- fused fp32 -> bf16 pack for x + all 4 weights ----------------
__global__ void pack_all(const float* __restrict__ x,
                         const float* __restrict__ Wl1, const float* __restrict__ Wr1,
                         const float* __restrict__ Wl2, const float* __restrict__ Wr2,
                         unsigned short* __restrict__ xb, unsigned short* __restrict__ Wc1,
                         unsigned short* __restrict__ Wc2, int n4x) {
  int i = blockIdx.x * blockDim.x + threadIdx.x;
  const float* src;
  unsigned short* dst;
  int local;
  if (i < n4x) { src = x; dst = xb; local = i; }
  else {
    int j = i - n4x;
    if (j < 8192) { src = Wl1; dst = Wc1; local = j; }
    else if (j < 16384) { src = Wr1; dst = Wc1 + 32768; local = j - 8192; }
    else if (j < 20480) { src = Wl2; dst = Wc2; local = j - 16384; }
    else if (j < 24576) { src = Wr2; dst = Wc2 + 16384; local = j - 20480; }
    else return;
  }
  float4 v = ((const float4*)src)[local];
  ushort4 o;
  o.x = f2bf(v.x); o.y = f2bf(v.y); o.z = f2bf(v.z); o.w = f2bf(v.w);
  ((ushort4*)dst)[local] = o;
}

// ---------------- MFMA GEMM: C[M,512](bf16) = A[M,K](bf16) @ W[512,K](bf16)^T + bias
// Block = 4 waves sharing ONE 64-row A tile (L1 reuse); wave wv covers n0=y*256+wv*64.
#define MFMA16 __builtin_amdgcn_mfma_f32_16x16x32_bf16
template <int K>
__global__ __launch_bounds__(256, 2) void mfma_gemm(
    const unsigned short* __restrict__ A, const unsigned short* __restrict__ W,
    const float* __restrict__ bl, const float* __restrict__ br,
    unsigned short* __restrict__ C, int M) {
  int lane = threadIdx.x & 63;
  int wv = threadIdx.x >> 6;
  int m0 = blockIdx.x * 64;
  int n0 = blockIdx.y * 256 + wv * 64;
  int lr = lane & 15, lk = (lane >> 4) * 8;
  const float* bp = (n0 < 256) ? bl : br;
  int nb = n0 & 255;

  short8 bfrag[4][K / 32];
#pragma unroll
  for (int nf = 0; nf < 4; ++nf)
#pragma unroll
    for (int ks = 0; ks < K / 32; ++ks)
      bfrag[nf][ks] = *(const short8*)&W[(size_t)(n0 + nf * 16 + lr) * K + ks * 32 + lk];

  f32x4 acc[4][4];
#pragma unroll
  for (int i = 0; i < 4; ++i)
#pragma unroll
    for (int j = 0; j < 4; ++j) acc[i][j] = (f32x4){0.f, 0.f, 0.f, 0.f};

#pragma unroll
  for (int mf = 0; mf < 4; ++mf) {
    int mr = m0 + mf * 16 + lr;
    int mrc = mr < M ? mr : 0;
    short8 afrag[K / 32];
#pragma unroll
    for (int ks = 0; ks < K / 32; ++ks)
      afrag[ks] = *(const short8*)&A[(size_t)mrc * K + ks * 32 + lk];
#pragma unroll
    for (int ks = 0; ks < K / 32; ++ks)
#pragma unroll
      for (int nf = 0; nf < 4; ++nf)
        acc[mf][nf] = MFMA16(afrag[ks], bfrag[nf][ks], acc[mf][nf], 0, 0, 0);
  }

  int cr = (lane >> 4) * 4;
#pragma unroll
  for (int mf = 0; mf < 4; ++mf) {
#pragma unroll
    for (int r = 0; r < 4; ++r) {
      int m = m0 + mf * 16 + cr + r;
      if (m < M) {
#pragma unroll
        for (int nf = 0; nf < 4; ++nf) {
          int n = n0 + nf * 16 + lr;
          float v = acc[mf][nf][r] + bp[nb + nf * 16 + lr];
          C[(size_t)m * HD + n] = f2bf(v);
        }
      }
    }
  }
}

// ---------------- Fused GATv2 per-node aggregate + LN + ELU (+ MLP) ----------------
// One wave per node; lane l owns channels 4l..4l+3; the 4 sixteen-lane rows = 4 heads
// (per-lane ssum IS the per-head denominator — no cross-row reduce on it).
// 16-edge prefetch ring (4 groups of 4): gather loads issued 12 edges (~840 cy of
// cover) ahead of use to hide ~900 cy HBM-miss latency.
template <bool LAST>
__global__ __launch_bounds__(256) void gat_kernel(
    const unsigned short* __restrict__ xlr,
    const float* __restrict__ att, const float* __restrict__ bias,
    const float* __restrict__ gamma, const float* __restrict__ beta,
    const int* __restrict__ row_start, const int* __restrict__ csr_src,
    const float* __restrict__ Wh1, const float* __restrict__ bh1,
    const float* __restrict__ Wh2, const float* __restrict__ bh2,
    void* __restrict__ outp, int N) {
  __shared__ float sh[4][96];
  int wid = threadIdx.x >> 6;
  int lane = threadIdx.x & 63;
  int v = blockIdx.x * 4 + wid;
  if (v >= N) return;
  int c0 = 4 * lane;
  int cc = 4 * (lane & 15);

  uint2 ur = *(const uint2*)&xlr[(size_t)v * HD + 256 + c0];
  float xr0 = ubits(ur.x << 16), xr1 = ubits(ur.x & 0xffff0000u);
  float xr2 = ubits(ur.y << 16), xr3 = ubits(ur.y & 0xffff0000u);
  float4 at4 = *(const float4*)&att[c0];

  float sA = 0.f, sB = 0.f;
  float aA0 = 0.f, aA1 = 0.f, aA2 = 0.f, aA3 = 0.f;
  float aB0 = 0.f, aB1 = 0.f, aB2 = 0.f, aB3 = 0.f;

  int rs = __builtin_amdgcn_readfirstlane(row_start[v]);
  int re = __builtin_amdgcn_readfirstlane(row_start[v + 1]);

  auto fetchi = [&](int i) -> uint2 {
    int ic = i < re ? i : re - 1;  // clamp; masked at accumulate
    int s = csr_src[ic];
    return *(const uint2*)&xlr[(size_t)s * HD + c0];
  };
  auto edge = [&](uint2 u, bool valid, float& ss, float& a0, float& a1,
                  float& a2, float& a3) {
    float x0 = ubits(u.x << 16), x1 = ubits(u.x & 0xffff0000u);
    float x2 = ubits(u.y << 16), x3 = ubits(u.y & 0xffff0000u);
    float t0 = x0 + xr0, t1 = x1 + xr1, t2 = x2 + xr2, t3 = x3 + xr3;
    // sum(att*leaky(t)) = 0.6*sum(att*t) + 0.4*sum(att*|t|)
    float p6 = t0 * at4.x;
    p6 = fmaf(t1, at4.y, p6);
    p6 = fmaf(t2, at4.z, p6);
    p6 = fmaf(t3, at4.w, p6);
    float p4 = fabsf(t0) * at4.x;
    p4 = fmaf(fabsf(t1), at4.y, p4);
    p4 = fmaf(fabsf(t2), at4.z, p4);
    p4 = fmaf(fabsf(t3), at4.w, p4);
    float sc = fmaf(0.4f, p4, 0.6f * p6);
    sc = dpp_add<0x121>(sc);  // row_ror:1
    sc = dpp_add<0x122>(sc);  // row_ror:2
    sc = dpp_add<0x124>(sc);  // row_ror:4
    sc = dpp_add<0x128>(sc);  // row_ror:8 -> 16-lane (per-head) sum
    float p = __expf(sc);  // scores O(1): softmax shift not needed
    p = valid ? p : 0.f;
    ss += p;
    a0 = fmaf(p, t0, a0);  // accumulate p*t; undo +xr after loop
    a1 = fmaf(p, t1, a1);
    a2 = fmaf(p, t2, a2);
    a3 = fmaf(p, t3, a3);
  };

  uint2 A0, A1, A2, A3, B0, B1, B2, B3, C0, C1, C2, C3, D0, D1, D2, D3;
  A0 = fetchi(rs); A1 = fetchi(rs + 1); A2 = fetchi(rs + 2); A3 = fetchi(rs + 3);
  B0 = fetchi(rs + 4); B1 = fetchi(rs + 5); B2 = fetchi(rs + 6); B3 = fetchi(rs + 7);
  C0 = fetchi(rs + 8); C1 = fetchi(rs + 9); C2 = fetchi(rs + 10); C3 = fetchi(rs + 11);
  int b = rs;
  while (true) {
    D0 = fetchi(b + 12); D1 = fetchi(b + 13); D2 = fetchi(b + 14); D3 = fetchi(b + 15);
    edge(A0, true, sA, aA0, aA1, aA2, aA3);
    edge(A1, b + 1 < re, sB, aB0, aB1, aB2, aB3);
    edge(A2, b + 2 < re, sA, aA0, aA1, aA2, aA3);
    edge(A3, b + 3 < re, sB, aB0, aB1, aB2, aB3);
    b += 4;
    if (b >= re) break;
    A0 = fetchi(b + 12); A1 = fetchi(b + 13); A2 = fetchi(b + 14); A3 = fetchi(b + 15);
    edge(B0, true, sA, aA0, aA1, aA2, aA3);
    edge(B1, b + 1 < re, sB, aB0, aB1, aB2, aB3);
    edge(B2, b + 2 < re, sA, aA0, aA1, aA2, aA3);
    edge(B3, b + 3 < re, sB, aB0, aB1, aB2, aB3);
    b += 4;
    if (b >= re) break;
    B0 = fetchi(b + 12); B1 = fetchi(b + 13); B2 = fetchi(b + 14); B3 = fetchi(b + 15);
    edge(C0, true, sA, aA0, aA1, aA2, aA3);
    edge(C1, b + 1 < re, sB, aB0, aB1, aB2, aB3);
    edge(C2, b + 2 < re, sA, aA0, aA1, aA2, aA3);
    edge(C3, b + 3 < re, sB, aB0, aB1, aB2, aB3);
    b += 4;
    if (b >= re) break;
    C0 = fetchi(b + 12); C1 = fetchi(b + 13); C2 = fetchi(b + 14); C3 = fetchi(b + 15);
    edge(D0, true, sA, aA0, aA1, aA2, aA3);
    edge(D1, b + 1 < re, sB, aB0, aB1, aB2, aB3);
    edge(D2, b + 2 < re, sA, aA0, aA1, aA2, aA3);
    edge(D3, b + 3 < re, sB, aB0, aB1, aB2, aB3);
    b += 4;
    if (b >= re) break;
  }

  // per-lane (= per-head) softmax denominator; no cross-row reduction here
  float inv = 1.f / (sA + sB);  // self-loop guarantees > 0

  float am[4] = {aA0 + aB0, aA1 + aB1, aA2 + aB2, aA3 + aB3};
  float xrv[4] = {xr0, xr1, xr2, xr3};
  float hv[4];
#pragma unroll
  for (int j = 0; j < 4; ++j) {
    float a = fmaf(am[j], inv, -xrv[j]);  // normalize per-head, undo +xr
    a += __shfl_xor(a, 16);               // then sum the 4 heads
    a += __shfl_xor(a, 32);
    hv[j] = a;
  }
  float4 bias4 = *(const float4*)&bias[cc];
  hv[0] = 0.25f * hv[0] + bias4.x;
  hv[1] = 0.25f * hv[1] + bias4.y;
  hv[2] = 0.25f * hv[2] + bias4.z;
  hv[3] = 0.25f * hv[3] + bias4.w;
  float psum = hv[0] + hv[1] + hv[2] + hv[3];
  float psq = hv[0] * hv[0] + hv[1] * hv[1] + hv[2] * hv[2] + hv[3] * hv[3];
#pragma unroll
  for (int o = 1; o < 16; o <<= 1) {
    psum += __shfl_xor(psum, o);
    psq += __shfl_xor(psq, o);
  }
  float mean = psum * (1.f / 64.f);
  float var = psq * (1.f / 64.f) - mean * mean;
  float rstd = rsqrtf(var + 1e-5f);
  float4 g4 = *(const float4*)&gamma[cc];
  float4 be4 = *(const float4*)&beta[cc];
  float y[4];
  y[0] = (hv[0] - mean) * rstd * g4.x + be4.x;
  y[1] = (hv[1] - mean) * rstd * g4.y + be4.y;
  y[2] = (hv[2] - mean) * rstd * g4.z + be4.z;
  y[3] = (hv[3] - mean) * rstd * g4.w + be4.w;
#pragma unroll
  for (int j = 0; j < 4; ++j)
    y[j] = y[j] > 0.f ? y[j] : (__expf(y[j]) - 1.f);  // fast ELU (abs err << 4e-3)

  if (!LAST) {
    if (lane < 16) {
      ushort4 o;
      o.x = f2bf(y[0]); o.y = f2bf(y[1]); o.z = f2bf(y[2]); o.w = f2bf(y[3]);
      *(ushort4*)&((unsigned short*)outp)[(size_t)v * HIDC + cc] = o;
    }
  } else {
    float* out = (float*)outp;
    if (lane < 16) {
      sh[wid][cc + 0] = y[0]; sh[wid][cc + 1] = y[1];
      sh[wid][cc + 2] = y[2]; sh[wid][cc + 3] = y[3];
    }
    if (lane < 32) {  // same-wave LDS ordering; waves independent
      float a = bh1[lane];
      const float4* wrow = (const float4*)&Wh1[lane * 64];
#pragma unroll
      for (int k = 0; k < 16; ++k) {
        float4 w4 = wrow[k];
        float4 s4 = *(const float4*)&sh[wid][4 * k];
        a = fmaf(s4.x, w4.x, a); a = fmaf(s4.y, w4.y, a);
        a = fmaf(s4.z, w4.z, a); a = fmaf(s4.w, w4.w, a);
      }
      sh[wid][64 + lane] = fmaxf(a, 0.f);
    }
    if (lane < 2) {
      float o = bh2[lane];
      const float4* wrow = (const float4*)&Wh2[lane * 32];
#pragma unroll
      for (int k = 0; k < 8; ++k) {
        float4 w4 = wrow[k];
        float4 s4 = *(const float4*)&sh[wid][64 + 4 * k];
        o = fmaf(s4.x, w4.x, o); o = fmaf(s4.y, w4.y, o);
        o = fmaf(s4.z, w4.z, o); o = fmaf(s4.w, w4.w, o);
      }
      out[(size_t)v * 2 + lane] = o;
    }
  }
}

// ---------------- launch ----------------
extern "C" void kernel_launch(void* const* d_in, const int* in_sizes, int n_in,
                              void* d_out, int out_size, void* d_ws, size_t ws_size,
                              hipStream_t stream) {
  const float* x = (const float*)d_in[0];
  const int* ei = (const int*)d_in[1];
  const float* Wl1 = (const float*)d_in[2]; const float* bl1 = (const float*)d_in[3];
  const float* Wr1 = (const float*)d_in[4]; const float* br1 = (const float*)d_in[5];
  const float* att1 = (const float*)d_in[6]; const float* bias1 = (const float*)d_in[7];
  const float* Wl2 = (const float*)d_in[8]; const float* bl2 = (const float*)d_in[9];
  const float* Wr2 = (const float*)d_in[10]; const float* br2 = (const float*)d_in[11];
  const float* att2 = (const float*)d_in[12]; const float* bias2 = (const float*)d_in[13];
  const float* g1 = (const float*)d_in[14]; const float* be1 = (const float*)d_in[15];
  const float* g2 = (const float*)d_in[16]; const float* be2 = (const float*)d_in[17];
  const float* Wh1 = (const float*)d_in[18]; const float* bh1 = (const float*)d_in[19];
  const float* Wh2 = (const float*)d_in[20]; const float* bh2 = (const float*)d_in[21];
  float* out = (float*)d_out;

  int N = in_sizes[0] / 128;
  int E = in_sizes[1] / 2;
  int ET = E + N;

  char* ws = (char*)d_ws;
  size_t off = 0;
  auto alloc = [&](size_t bytes) {
    void* p = ws + off;
    off += (bytes + 255) & ~(size_t)255;
    return p;
  };
  unsigned short* xlr = (unsigned short*)alloc((size_t)N * HD * 2);
  unsigned short* xb  = (unsigned short*)alloc((size_t)N * 128 * 2);
  unsigned short* h1b = (unsigned short*)alloc((size_t)N * HIDC * 2);
  unsigned short* Wc1 = (unsigned short*)alloc((size_t)512 * 128 * 2);
  unsigned short* Wc2 = (unsigned short*)alloc((size_t)512 * 64 * 2);
  int* row_start = (int*)alloc((size_t)(N + 1) * 4);
  int* counts = (int*)alloc((size_t)N * 4);
  int* cursor = (int*)alloc((size_t)N * 4);
  int* csr = (int*)alloc((size_t)ET * 4);

  hipMemsetAsync(counts, 0, (size_t)N * 4, stream);
  hipMemsetAsync(cursor, 0, (size_t)N * 4, stream);

  int eb = (ET + 255) / 256;
  count_kernel<<<eb, 256, 0, stream>>>(ei, E, N, counts);
  scan_kernel<<<1, 1024, 0, stream>>>(counts, row_start, N);
  scatter_kernel<<<eb, 256, 0, stream>>>(ei, E, N, row_start, cursor, csr);

  int n4x = N * 128 / 4;
  int tot4 = n4x + 24576;
  pack_all<<<(tot4 + 255) / 256, 256, 0, stream>>>(x, Wl1, Wr1, Wl2, Wr2,
                                                   xb, Wc1, Wc2, n4x);

  dim3 gg((N + 63) / 64, 2);
  mfma_gemm<128><<<gg, 256, 0, stream>>>(xb, Wc1, bl1, br1, xlr, N);

  int gb = (N + 3) / 4;
  gat_kernel<false><<<gb, 256, 0, stream>>>(xlr, att1, bias1, g1, be1,
                                            row_start, csr, nullptr, nullptr,
                                            nullptr, nullptr, h1b, N);

  mfma_gemm<64><<<gg, 256, 0, stream>>>(h1b, Wc2, bl2, br2, xlr, N);

  gat_kernel<true><<<gb, 256, 0, stream>>>(xlr, att2, bias2, g2, be2,
                                           row_start, csr, Wh1, bh1, Wh2, bh2,
                                           out, N);
}

// Round 9
// 343.020 us; speedup vs baseline: 1.1166x; 1.0368x over previous
//
#include <hip/hip_runtime.h>
#include <math.h>

#define HIDC 64
#define HD 512  // combined xl|xr channels per node (bf16)
#define SCHUNK 4096

typedef unsigned int uint32;
using short8 = __attribute__((ext_vector_type(8))) short;
using f32x4 = __attribute__((ext_vector_type(4))) float;

__device__ inline float ubits(uint32 u) { return __builtin_bit_cast(float, u); }
__device__ inline unsigned short f2bf(float x) {
  uint32 u = __builtin_bit_cast(uint32, x);
  return (unsigned short)((u + 0x7fffu + ((u >> 16) & 1u)) >> 16);
}

template <int CTRL>
__device__ inline float dpp_add(float x) {
  int xi = __builtin_bit_cast(int, x);
  int s = __builtin_amdgcn_update_dpp(0, xi, CTRL, 0xf, 0xf, true);
  return x + __builtin_bit_cast(float, s);
}

// ---------------- CSR build ----------------
__global__ void count_kernel(const int* __restrict__ ei, int E, int N,
                             int* __restrict__ counts) {
  int e = blockIdx.x * blockDim.x + threadIdx.x;
  int etot = E + N;
  if (e >= etot) return;
  int dst = (e < E) ? ei[E + e] : (e - E);
  atomicAdd(&counts[dst], 1);
}

// 3-phase multi-block scan (50K elems): block sums -> scan partials -> local scans
__global__ __launch_bounds__(1024) void scan_p1(const int* __restrict__ counts,
                                                int* __restrict__ bsum, int n) {
  __shared__ int wsum[16];
  int tid = threadIdx.x;
  int lane = tid & 63, wid = tid >> 6;
  int i0 = blockIdx.x * SCHUNK + tid * 4;
  int s = 0;
  if (i0 + 3 < n) {
    int4 c = *(const int4*)&counts[i0];
    s = c.x + c.y + c.z + c.w;
  } else {
    if (i0 + 0 < n) s += counts[i0 + 0];
    if (i0 + 1 < n) s += counts[i0 + 1];
    if (i0 + 2 < n) s += counts[i0 + 2];
    if (i0 + 3 < n) s += counts[i0 + 3];
  }
#pragma unroll
  for (int o = 1; o < 64; o <<= 1) s += __shfl_xor(s, o, 64);
  if (lane == 0) wsum[wid] = s;
  __syncthreads();
  if (wid == 0) {
    int v = (lane < 16) ? wsum[lane] : 0;
#pragma unroll
    for (int o = 1; o < 16; o <<= 1) v += __shfl_xor(v, o, 64);
    if (lane == 0) bsum[blockIdx.x] = v;
  }
}

__global__ void scan_p2(const int* __restrict__ bsum, int* __restrict__ boff, int nb) {
  int lane = threadIdx.x;
  int v = (lane < nb) ? bsum[lane] : 0;
  // inclusive prefix across 64 lanes, then make exclusive
  int inc = v;
#pragma unroll
  for (int o = 1; o < 64; o <<= 1) {
    int t = __shfl_up(inc, o, 64);
    if (lane >= o) inc += t;
  }
  if (lane < nb) boff[lane] = inc - v;  // exclusive
}

__global__ __launch_bounds__(1024) void scan_p3(const int* __restrict__ counts,
                                                const int* __restrict__ boff,
                                                int* __restrict__ row_start, int n) {
  __shared__ int wsum[16];
  int tid = threadIdx.x;
  int lane = tid & 63, wid = tid >> 6;
  int base = blockIdx.x * SCHUNK;
  int i0 = base + tid * 4;
  if (blockIdx.x == 0 && tid == 0) row_start[0] = 0;
  int4 c = make_int4(0, 0, 0, 0);
  if (i0 + 3 < n) c = *(const int4*)&counts[i0];
  else {
    if (i0 + 0 < n) c.x = counts[i0 + 0];
    if (i0 + 1 < n) c.y = counts[i0 + 1];
    if (i0 + 2 < n) c.z = counts[i0 + 2];
    if (i0 + 3 < n) c.w = counts[i0 + 3];
  }
  int s1 = c.x + c.y, s2 = s1 + c.z, s3 = s2 + c.w;
  int x = s3;
#pragma unroll
  for (int o = 1; o < 64; o <<= 1) {
    int t = __shfl_up(x, o, 64);
    if (lane >= o) x += t;
  }
  if (lane == 63) wsum[wid] = x;
  __syncthreads();
  if (wid == 0) {
    int v = (lane < 16) ? wsum[lane] : 0;
#pragma unroll
    for (int o = 1; o < 16; o <<= 1) {
      int t = __shfl_up(v, o, 64);
      if (lane >= o) v += t;
    }
    if (lane < 16) wsum[lane] = v;
  }
  __syncthreads();
  int pre = (wid > 0 ? wsum[wid - 1] : 0) + boff[blockIdx.x] + (x - s3);
  if (i0 + 0 < n) row_start[i0 + 1] = pre + c.x;
  if (i0 + 1 < n) row_start[i0 + 2] = pre + s1;
  if (i0 + 2 < n) row_start[i0 + 3] = pre + s2;
  if (i0 + 3 < n) row_start[i0 + 4] = pre + s3;
}

// cursor-free scatter: counts holds degrees (dead after scan) -> atomicSub
__global__ void scatter_kernel(const int* __restrict__ ei, int E, int N,
                               const int* __restrict__ row_start,
                               int* __restrict__ counts, int* __restrict__ csr_src) {
  int e = blockIdx.x * blockDim.x + threadIdx.x;
  int etot = E + N;
  if (e >= etot) return;
  int src, dst;
  if (e < E) { src = ei[e]; dst = ei[E + e]; } else { src = e - E; dst = src; }
  int pos = row_start[dst] + atomicSub(&counts[dst], 1) - 1;
  csr_src[pos] = src;
}

// ---------------- fused fp32 -> bf16 pack for x + all 4 weights ----------------
__global__ void pack_all(const float* __restrict__ x,
                         const float* __restrict__ Wl1, const float* __restrict__ Wr1,
                         const float* __restrict__ Wl2, const float* __restrict__ Wr2,
                         unsigned short* __restrict__ xb, unsigned short* __restrict__ Wc1,
                         unsigned short* __restrict__ Wc2, int n4x) {
  int i = blockIdx.x * blockDim.x + threadIdx.x;
  const float* src;
  unsigned short* dst;
  int local;
  if (i < n4x) { src = x; dst = xb; local = i; }
  else {
    int j = i - n4x;
    if (j < 8192) { src = Wl1; dst = Wc1; local = j; }
    else if (j < 16384) { src = Wr1; dst = Wc1 + 32768; local = j - 8192; }
    else if (j < 20480) { src = Wl2; dst = Wc2; local = j - 16384; }
    else if (j < 24576) { src = Wr2; dst = Wc2 + 16384; local = j - 20480; }
    else return;
  }
  float4 v = ((const float4*)src)[local];
  ushort4 o;
  o.x = f2bf(v.x); o.y = f2bf(v.y); o.z = f2bf(v.z); o.w = f2bf(v.w);
  ((ushort4*)dst)[local] = o;
}

// ---------------- MFMA GEMM: C[M,512](bf16) = A[M,K](bf16) @ W[512,K](bf16)^T + bias
#define MFMA16 __builtin_amdgcn_mfma_f32_16x16x32_bf16
template <int K>
__global__ __launch_bounds__(256, 2) void mfma_gemm(
    const unsigned short* __restrict__ A, const unsigned short* __restrict__ W,
    const float* __restrict__ bl, const float* __restrict__ br,
    unsigned short* __restrict__ C, int M) {
  int lane = threadIdx.x & 63;
  int wv = threadIdx.x >> 6;
  int m0 = blockIdx.x * 64;
  int n0 = blockIdx.y * 256 + wv * 64;
  int lr = lane & 15, lk = (lane >> 4) * 8;
  const float* bp = (n0 < 256) ? bl : br;
  int nb = n0 & 255;

  short8 bfrag[4][K / 32];
#pragma unroll
  for (int nf = 0; nf < 4; ++nf)
#pragma unroll
    for (int ks = 0; ks < K / 32; ++ks)
      bfrag[nf][ks] = *(const short8*)&W[(size_t)(n0 + nf * 16 + lr) * K + ks * 32 + lk];

  f32x4 acc[4][4];
#pragma unroll
  for (int i = 0; i < 4; ++i)
#pragma unroll
    for (int j = 0; j < 4; ++j) acc[i][j] = (f32x4){0.f, 0.f, 0.f, 0.f};

#pragma unroll
  for (int mf = 0; mf < 4; ++mf) {
    int mr = m0 + mf * 16 + lr;
    int mrc = mr < M ? mr : 0;
    short8 afrag[K / 32];
#pragma unroll
    for (int ks = 0; ks < K / 32; ++ks)
      afrag[ks] = *(const short8*)&A[(size_t)mrc * K + ks * 32 + lk];
#pragma unroll
    for (int ks = 0; ks < K / 32; ++ks)
#pragma unroll
      for (int nf = 0; nf < 4; ++nf)
        acc[mf][nf] = MFMA16(afrag[ks], bfrag[nf][ks], acc[mf][nf], 0, 0, 0);
  }

  int cr = (lane >> 4) * 4;
#pragma unroll
  for (int mf = 0; mf < 4; ++mf) {
#pragma unroll
    for (int r = 0; r < 4; ++r) {
      int m = m0 + mf * 16 + cr + r;
      if (m < M) {
#pragma unroll
        for (int nf = 0; nf < 4; ++nf) {
          int n = n0 + nf * 16 + lr;
          float v = acc[mf][nf][r] + bp[nb + nf * 16 + lr];
          C[(size_t)m * HD + n] = f2bf(v);
        }
      }
    }
  }
}

// ---------------- Fused GATv2 per-node aggregate + LN + ELU (+ MLP) ----------------
// One wave per node; lane l owns channels 4l..4l+3; the 4 sixteen-lane rows = 4 heads
// (per-lane ssum IS the per-head denominator — no cross-row reduce on it).
// NOTE (R5-R8 evidence): this kernel is pinned at FETCH/1.7 TB/s (L2-miss-path wall);
// VALU/prefetch changes don't move it. Do not "optimize" the loop further.
template <bool LAST>
__global__ __launch_bounds__(256) void gat_kernel(
    const unsigned short* __restrict__ xlr,
    const float* __restrict__ att, const float* __restrict__ bias,
    const float* __restrict__ gamma, const float* __restrict__ beta,
    const int* __restrict__ row_start, const int* __restrict__ csr_src,
    const float* __restrict__ Wh1, const float* __restrict__ bh1,
    const float* __restrict__ Wh2, const float* __restrict__ bh2,
    void* __restrict__ outp, int N) {
  __shared__ float sh[4][96];
  int wid = threadIdx.x >> 6;
  int lane = threadIdx.x & 63;
  int v = blockIdx.x * 4 + wid;
  if (v >= N) return;
  int c0 = 4 * lane;
  int cc = 4 * (lane & 15);

  uint2 ur = *(const uint2*)&xlr[(size_t)v * HD + 256 + c0];
  float xr0 = ubits(ur.x << 16), xr1 = ubits(ur.x & 0xffff0000u);
  float xr2 = ubits(ur.y << 16), xr3 = ubits(ur.y & 0xffff0000u);
  float4 at4 = *(const float4*)&att[c0];

  float sA = 0.f, sB = 0.f;
  float aA0 = 0.f, aA1 = 0.f, aA2 = 0.f, aA3 = 0.f;
  float aB0 = 0.f, aB1 = 0.f, aB2 = 0.f, aB3 = 0.f;

  int rs = __builtin_amdgcn_readfirstlane(row_start[v]);
  int re = __builtin_amdgcn_readfirstlane(row_start[v + 1]);

  auto fetchi = [&](int i) -> uint2 {
    int ic = i < re ? i : re - 1;  // clamp; masked at accumulate
    int s = csr_src[ic];
    return *(const uint2*)&xlr[(size_t)s * HD + c0];
  };
  auto edge = [&](uint2 u, bool valid, float& ss, float& a0, float& a1,
                  float& a2, float& a3) {
    float x0 = ubits(u.x << 16), x1 = ubits(u.x & 0xffff0000u);
    float x2 = ubits(u.y << 16), x3 = ubits(u.y & 0xffff0000u);
    float t0 = x0 + xr0, t1 = x1 + xr1, t2 = x2 + xr2, t3 = x3 + xr3;
    // sum(att*leaky(t)) = 0.6*sum(att*t) + 0.4*sum(att*|t|)
    float p6 = t0 * at4.x;
    p6 = fmaf(t1, at4.y, p6);
    p6 = fmaf(t2, at4.z, p6);
    p6 = fmaf(t3, at4.w, p6);
    float p4 = fabsf(t0) * at4.x;
    p4 = fmaf(fabsf(t1), at4.y, p4);
    p4 = fmaf(fabsf(t2), at4.z, p4);
    p4 = fmaf(fabsf(t3), at4.w, p4);
    float sc = fmaf(0.4f, p4, 0.6f * p6);
    sc = dpp_add<0x121>(sc);  // row_ror:1
    sc = dpp_add<0x122>(sc);  // row_ror:2
    sc = dpp_add<0x124>(sc);  // row_ror:4
    sc = dpp_add<0x128>(sc);  // row_ror:8 -> 16-lane (per-head) sum
    float p = __expf(sc);  // scores O(1): softmax shift not needed
    p = valid ? p : 0.f;
    ss += p;
    a0 = fmaf(p, t0, a0);  // accumulate p*t; undo +xr after loop
    a1 = fmaf(p, t1, a1);
    a2 = fmaf(p, t2, a2);
    a3 = fmaf(p, t3, a3);
  };

  uint2 A0, A1, A2, A3, B0, B1, B2, B3, C0, C1, C2, C3, D0, D1, D2, D3;
  A0 = fetchi(rs); A1 = fetchi(rs + 1); A2 = fetchi(rs + 2); A3 = fetchi(rs + 3);
  B0 = fetchi(rs + 4); B1 = fetchi(rs + 5); B2 = fetchi(rs + 6); B3 = fetchi(rs + 7);
  C0 = fetchi(rs + 8); C1 = fetchi(rs + 9); C2 = fetchi(rs + 10); C3 = fetchi(rs + 11);
  int b = rs;
  while (true) {
    D0 = fetchi(b + 12); D1 = fetchi(b + 13); D2 = fetchi(b + 14); D3 = fetchi(b + 15);
    edge(A0, true, sA, aA0, aA1, aA2, aA3);
    edge(A1, b + 1 < re, sB, aB0, aB1, aB2, aB3);
    edge(A2, b + 2 < re, sA, aA0, aA1, aA2, aA3);
    edge(A3, b + 3 < re, sB, aB0, aB1, aB2, aB3);
    b += 4;
    if (b >= re) break;
    A0 = fetchi(b + 12); A1 = fetchi(b + 13); A2 = fetchi(b + 14); A3 = fetchi(b + 15);
    edge(B0, true, sA, aA0, aA1, aA2, aA3);
    edge(B1, b + 1 < re, sB, aB0, aB1, aB2, aB3);
    edge(B2, b + 2 < re, sA, aA0, aA1, aA2, aA3);
    edge(B3, b + 3 < re, sB, aB0, aB1, aB2, aB3);
    b += 4;
    if (b >= re) break;
    B0 = fetchi(b + 12); B1 = fetchi(b + 13); B2 = fetchi(b + 14); B3 = fetchi(b + 15);
    edge(C0, true, sA, aA0, aA1, aA2, aA3);
    edge(C1, b + 1 < re, sB, aB0, aB1, aB2, aB3);
    edge(C2, b + 2 < re, sA, aA0, aA1, aA2, aA3);
    edge(C3, b + 3 < re, sB, aB0, aB1, aB2, aB3);
    b += 4;
    if (b >= re) break;
    C0 = fetchi(b + 12); C1 = fetchi(b + 13); C2 = fetchi(b + 14); C3 = fetchi(b + 15);
    edge(D0, true, sA, aA0, aA1, aA2, aA3);
    edge(D1, b + 1 < re, sB, aB0, aB1, aB2, aB3);
    edge(D2, b + 2 < re, sA, aA0, aA1, aA2, aA3);
    edge(D3, b + 3 < re, sB, aB0, aB1, aB2, aB3);
    b += 4;
    if (b >= re) break;
  }

  // per-lane (= per-head) softmax denominator; no cross-row reduction here
  float inv = 1.f / (sA + sB);  // self-loop guarantees > 0

  float am[4] = {aA0 + aB0, aA1 + aB1, aA2 + aB2, aA3 + aB3};
  float xrv[4] = {xr0, xr1, xr2, xr3};
  float hv[4];
#pragma unroll
  for (int j = 0; j < 4; ++j) {
    float a = fmaf(am[j], inv, -xrv[j]);  // normalize per-head, undo +xr
    a += __shfl_xor(a, 16);               // then sum the 4 heads
    a += __shfl_xor(a, 32);
    hv[j] = a;
  }
  float4 bias4 = *(const float4*)&bias[cc];
  hv[0] = 0.25f * hv[0] + bias4.x;
  hv[1] = 0.25f * hv[1] + bias4.y;
  hv[2] = 0.25f * hv[2] + bias4.z;
  hv[3] = 0.25f * hv[3] + bias4.w;
  float psum = hv[0] + hv[1] + hv[2] + hv[3];
  float psq = hv[0] * hv[0] + hv[1] * hv[1] + hv[2] * hv[2] + hv[3] * hv[3];
#pragma unroll
  for (int o = 1; o < 16; o <<= 1) {
    psum += __shfl_xor(psum, o);
    psq += __shfl_xor(psq, o);
  }
  float mean = psum * (1.f / 64.f);
  float var = psq * (1.f / 64.f) - mean * mean;
  float rstd = rsqrtf(var + 1e-5f);
  float4 g4 = *(const float4*)&gamma[cc];
  float4 be4 = *(const float4*)&beta[cc];
  float y[4];
  y[0] = (hv[0] - mean) * rstd * g4.x + be4.x;
  y[1] = (hv[1] - mean) * rstd * g4.y + be4.y;
  y[2] = (hv[2] - mean) * rstd * g4.z + be4.z;
  y[3] = (hv[3] - mean) * rstd * g4.w + be4.w;
#pragma unroll
  for (int j = 0; j < 4; ++j)
    y[j] = y[j] > 0.f ? y[j] : (__expf(y[j]) - 1.f);  // fast ELU (abs err << 4e-3)

  if (!LAST) {
    if (lane < 16) {
      ushort4 o;
      o.x = f2bf(y[0]); o.y = f2bf(y[1]); o.z = f2bf(y[2]); o.w = f2bf(y[3]);
      *(ushort4*)&((unsigned short*)outp)[(size_t)v * HIDC + cc] = o;
    }
  } else {
    float* out = (float*)outp;
    if (lane < 16) {
      sh[wid][cc + 0] = y[0]; sh[wid][cc + 1] = y[1];
      sh[wid][cc + 2] = y[2]; sh[wid][cc + 3] = y[3];
    }
    if (lane < 32) {  // same-wave LDS ordering; waves independent
      float a = bh1[lane];
      const float4* wrow = (const float4*)&Wh1[lane * 64];
#pragma unroll
      for (int k = 0; k < 16; ++k) {
        float4 w4 = wrow[k];
        float4 s4 = *(const float4*)&sh[wid][4 * k];
        a = fmaf(s4.x, w4.x, a); a = fmaf(s4.y, w4.y, a);
        a = fmaf(s4.z, w4.z, a); a = fmaf(s4.w, w4.w, a);
      }
      sh[wid][64 + lane] = fmaxf(a, 0.f);
    }
    if (lane < 2) {
      float o = bh2[lane];
      const float4* wrow = (const float4*)&Wh2[lane * 32];
#pragma unroll
      for (int k = 0; k < 8; ++k) {
        float4 w4 = wrow[k];
        float4 s4 = *(const float4*)&sh[wid][64 + 4 * k];
        o = fmaf(s4.x, w4.x, o); o = fmaf(s4.y, w4.y, o);
        o = fmaf(s4.z, w4.z, o); o = fmaf(s4.w, w4.w, o);
      }
      out[(size_t)v * 2 + lane] = o;
    }
  }
}

// ---------------- launch ----------------
extern "C" void kernel_launch(void* const* d_in, const int* in_sizes, int n_in,
                              void* d_out, int out_size, void* d_ws, size_t ws_size,
                              hipStream_t stream) {
  const float* x = (const float*)d_in[0];
  const int* ei = (const int*)d_in[1];
  const float* Wl1 = (const float*)d_in[2]; const float* bl1 = (const float*)d_in[3];
  const float* Wr1 = (const float*)d_in[4]; const float* br1 = (const float*)d_in[5];
  const float* att1 = (const float*)d_in[6]; const float* bias1 = (const float*)d_in[7];
  const float* Wl2 = (const float*)d_in[8]; const float* bl2 = (const float*)d_in[9];
  const float* Wr2 = (const float*)d_in[10]; const float* br2 = (const float*)d_in[11];
  const float* att2 = (const float*)d_in[12]; const float* bias2 = (const float*)d_in[13];
  const float* g1 = (const float*)d_in[14]; const float* be1 = (const float*)d_in[15];
  const float* g2 = (const float*)d_in[16]; const float* be2 = (const float*)d_in[17];
  const float* Wh1 = (const float*)d_in[18]; const float* bh1 = (const float*)d_in[19];
  const float* Wh2 = (const float*)d_in[20]; const float* bh2 = (const float*)d_in[21];
  float* out = (float*)d_out;

  int N = in_sizes[0] / 128;
  int E = in_sizes[1] / 2;
  int ET = E + N;

  char* ws = (char*)d_ws;
  size_t off = 0;
  auto alloc = [&](size_t bytes) {
    void* p = ws + off;
    off += (bytes + 255) & ~(size_t)255;
    return p;
  };
  unsigned short* xlr = (unsigned short*)alloc((size_t)N * HD * 2);
  unsigned short* xb  = (unsigned short*)alloc((size_t)N * 128 * 2);
  unsigned short* h1b = (unsigned short*)alloc((size_t)N * HIDC * 2);
  unsigned short* Wc1 = (unsigned short*)alloc((size_t)512 * 128 * 2);
  unsigned short* Wc2 = (unsigned short*)alloc((size_t)512 * 64 * 2);
  int* row_start = (int*)alloc((size_t)(N + 1) * 4);
  int* counts = (int*)alloc((size_t)N * 4);
  int* csr = (int*)alloc((size_t)ET * 4);
  int nsb = (N + SCHUNK - 1) / SCHUNK;  // 13 for N=50K (must be <= 64)
  int* bsum = (int*)alloc((size_t)nsb * 4);
  int* boff = (int*)alloc((size_t)nsb * 4);

  hipMemsetAsync(counts, 0, (size_t)N * 4, stream);

  int eb = (ET + 255) / 256;
  count_kernel<<<eb, 256, 0, stream>>>(ei, E, N, counts);
  scan_p1<<<nsb, 1024, 0, stream>>>(counts, bsum, N);
  scan_p2<<<1, 64, 0, stream>>>(bsum, boff, nsb);
  scan_p3<<<nsb, 1024, 0, stream>>>(counts, boff, row_start, N);
  scatter_kernel<<<eb, 256, 0, stream>>>(ei, E, N, row_start, counts, csr);

  int n4x = N * 128 / 4;
  int tot4 = n4x + 24576;
  pack_all<<<(tot4 + 255) / 256, 256, 0, stream>>>(x, Wl1, Wr1, Wl2, Wr2,
                                                   xb, Wc1, Wc2, n4x);

  dim3 gg((N + 63) / 64, 2);
  mfma_gemm<128><<<gg, 256, 0, stream>>>(xb, Wc1, bl1, br1, xlr, N);

  int gb = (N + 3) / 4;
  gat_kernel<false><<<gb, 256, 0, stream>>>(xlr, att1, bias1, g1, be1,
                                            row_start, csr, nullptr, nullptr,
                                            nullptr, nullptr, h1b, N);

  mfma_gemm<64><<<gg, 256, 0, stream>>>(h1b, Wc2, bl2, br2, xlr, N);

  gat_kernel<true><<<gb, 256, 0, stream>>>(xlr, att2, bias2, g2, be2,
                                           row_start, csr, Wh1, bh1, Wh2, bh2,
                                           out, N);
}

// Round 10
// 332.784 us; speedup vs baseline: 1.1510x; 1.0308x over previous
//
#include <hip/hip_runtime.h>
#include <math.h>

#define HIDC 64
#define HD 512  // combined xl|xr channels per node (bf16)
#define SCHUNK 4096

typedef unsigned int uint32;
using short8 = __attribute__((ext_vector_type(8))) short;
using f32x4 = __attribute__((ext_vector_type(4))) float;

__device__ inline float ubits(uint32 u) { return __builtin_bit_cast(float, u); }
__device__ inline unsigned short f2bf(float x) {
  uint32 u = __builtin_bit_cast(uint32, x);
  return (unsigned short)((u + 0x7fffu + ((u >> 16) & 1u)) >> 16);
}

template <int CTRL>
__device__ inline float dpp_add(float x) {
  int xi = __builtin_bit_cast(int, x);
  int s = __builtin_amdgcn_update_dpp(0, xi, CTRL, 0xf, 0xf, true);
  return x + __builtin_bit_cast(float, s);
}

// ---------------- prep: edge count + weight pack + x pack (independent block ranges)
__global__ void prep_kernel(const int* __restrict__ ei, int E, int N, int eb,
                            int* __restrict__ counts,
                            const float* __restrict__ x,
                            const float* __restrict__ Wl1, const float* __restrict__ Wr1,
                            const float* __restrict__ Wl2, const float* __restrict__ Wr2,
                            unsigned short* __restrict__ xb,
                            unsigned short* __restrict__ Wc1,
                            unsigned short* __restrict__ Wc2, int n4x) {
  int blk = blockIdx.x;
  if (blk < eb) {  // edge-count histogram
    int e = blk * blockDim.x + threadIdx.x;
    int etot = E + N;
    if (e >= etot) return;
    int dst = (e < E) ? ei[E + e] : (e - E);
    atomicAdd(&counts[dst], 1);
    return;
  }
  int j = (blk - eb) * blockDim.x + threadIdx.x;  // pack index (float4 granules)
  const float* src;
  unsigned short* dst;
  int local;
  if (j < 8192) { src = Wl1; dst = Wc1; local = j; }
  else if (j < 16384) { src = Wr1; dst = Wc1 + 32768; local = j - 8192; }
  else if (j < 20480) { src = Wl2; dst = Wc2; local = j - 16384; }
  else if (j < 24576) { src = Wr2; dst = Wc2 + 16384; local = j - 20480; }
  else if (j < 24576 + n4x) { src = x; dst = xb; local = j - 24576; }
  else return;
  float4 v = ((const float4*)src)[local];
  ushort4 o;
  o.x = f2bf(v.x); o.y = f2bf(v.y); o.z = f2bf(v.z); o.w = f2bf(v.w);
  ((ushort4*)dst)[local] = o;
}

// 2-phase multi-block scan: block sums, then local scans w/ inline partial-prefix
__global__ __launch_bounds__(1024) void scan_p1(const int* __restrict__ counts,
                                                int* __restrict__ bsum, int n) {
  __shared__ int wsum[16];
  int tid = threadIdx.x;
  int lane = tid & 63, wid = tid >> 6;
  int i0 = blockIdx.x * SCHUNK + tid * 4;
  int s = 0;
  if (i0 + 3 < n) {
    int4 c = *(const int4*)&counts[i0];
    s = c.x + c.y + c.z + c.w;
  } else {
    if (i0 + 0 < n) s += counts[i0 + 0];
    if (i0 + 1 < n) s += counts[i0 + 1];
    if (i0 + 2 < n) s += counts[i0 + 2];
    if (i0 + 3 < n) s += counts[i0 + 3];
  }
#pragma unroll
  for (int o = 1; o < 64; o <<= 1) s += __shfl_xor(s, o, 64);
  if (lane == 0) wsum[wid] = s;
  __syncthreads();
  if (wid == 0) {
    int v = (lane < 16) ? wsum[lane] : 0;
#pragma unroll
    for (int o = 1; o < 16; o <<= 1) v += __shfl_xor(v, o, 64);
    if (lane == 0) bsum[blockIdx.x] = v;
  }
}

__global__ __launch_bounds__(1024) void scan_p3(const int* __restrict__ counts,
                                                const int* __restrict__ bsum, int nsb,
                                                int* __restrict__ row_start, int n) {
  __shared__ int wsum[16];
  __shared__ int myoff;
  int tid = threadIdx.x;
  int lane = tid & 63, wid = tid >> 6;
  // wave 0: exclusive-prefix the <=64 block sums in-register, keep own offset
  if (wid == 0) {
    int v = (lane < nsb) ? bsum[lane] : 0;
    int inc = v;
#pragma unroll
    for (int o = 1; o < 64; o <<= 1) {
      int t = __shfl_up(inc, o, 64);
      if (lane >= o) inc += t;
    }
    if (lane == (int)blockIdx.x) myoff = inc - v;  // exclusive prefix for this block
  }
  int base = blockIdx.x * SCHUNK;
  int i0 = base + tid * 4;
  if (blockIdx.x == 0 && tid == 0) row_start[0] = 0;
  int4 c = make_int4(0, 0, 0, 0);
  if (i0 + 3 < n) c = *(const int4*)&counts[i0];
  else {
    if (i0 + 0 < n) c.x = counts[i0 + 0];
    if (i0 + 1 < n) c.y = counts[i0 + 1];
    if (i0 + 2 < n) c.z = counts[i0 + 2];
    if (i0 + 3 < n) c.w = counts[i0 + 3];
  }
  int s1 = c.x + c.y, s2 = s1 + c.z, s3 = s2 + c.w;
  int x = s3;
#pragma unroll
  for (int o = 1; o < 64; o <<= 1) {
    int t = __shfl_up(x, o, 64);
    if (lane >= o) x += t;
  }
  if (lane == 63) wsum[wid] = x;
  __syncthreads();
  if (wid == 0) {
    int v = (lane < 16) ? wsum[lane] : 0;
#pragma unroll
    for (int o = 1; o < 16; o <<= 1) {
      int t = __shfl_up(v, o, 64);
      if (lane >= o) v += t;
    }
    if (lane < 16) wsum[lane] = v;
  }
  __syncthreads();
  int pre = (wid > 0 ? wsum[wid - 1] : 0) + myoff + (x - s3);
  if (i0 + 0 < n) row_start[i0 + 1] = pre + c.x;
  if (i0 + 1 < n) row_start[i0 + 2] = pre + s1;
  if (i0 + 2 < n) row_start[i0 + 3] = pre + s2;
  if (i0 + 3 < n) row_start[i0 + 4] = pre + s3;
}

// cursor-free scatter: counts holds degrees (dead after scan) -> atomicSub
__global__ void scatter_kernel(const int* __restrict__ ei, int E, int N,
                               const int* __restrict__ row_start,
                               int* __restrict__ counts, int* __restrict__ csr_src) {
  int e = blockIdx.x * blockDim.x + threadIdx.x;
  int etot = E + N;
  if (e >= etot) return;
  int src, dst;
  if (e < E) { src = ei[e]; dst = ei[E + e]; } else { src = e - E; dst = src; }
  int pos = row_start[dst] + atomicSub(&counts[dst], 1) - 1;
  csr_src[pos] = src;
}

// ---------------- MFMA GEMM: C[M,512](bf16) = A[M,K](bf16) @ W[512,K](bf16)^T + bias
#define MFMA16 __builtin_amdgcn_mfma_f32_16x16x32_bf16
template <int K>
__global__ __launch_bounds__(256, 2) void mfma_gemm(
    const unsigned short* __restrict__ A, const unsigned short* __restrict__ W,
    const float* __restrict__ bl, const float* __restrict__ br,
    unsigned short* __restrict__ C, int M) {
  int lane = threadIdx.x & 63;
  int wv = threadIdx.x >> 6;
  int m0 = blockIdx.x * 64;
  int n0 = blockIdx.y * 256 + wv * 64;
  int lr = lane & 15, lk = (lane >> 4) * 8;
  const float* bp = (n0 < 256) ? bl : br;
  int nb = n0 & 255;

  short8 bfrag[4][K / 32];
#pragma unroll
  for (int nf = 0; nf < 4; ++nf)
#pragma unroll
    for (int ks = 0; ks < K / 32; ++ks)
      bfrag[nf][ks] = *(const short8*)&W[(size_t)(n0 + nf * 16 + lr) * K + ks * 32 + lk];

  f32x4 acc[4][4];
#pragma unroll
  for (int i = 0; i < 4; ++i)
#pragma unroll
    for (int j = 0; j < 4; ++j) acc[i][j] = (f32x4){0.f, 0.f, 0.f, 0.f};

#pragma unroll
  for (int mf = 0; mf < 4; ++mf) {
    int mr = m0 + mf * 16 + lr;
    int mrc = mr < M ? mr : 0;
    short8 afrag[K / 32];
#pragma unroll
    for (int ks = 0; ks < K / 32; ++ks)
      afrag[ks] = *(const short8*)&A[(size_t)mrc * K + ks * 32 + lk];
#pragma unroll
    for (int ks = 0; ks < K / 32; ++ks)
#pragma unroll
      for (int nf = 0; nf < 4; ++nf)
        acc[mf][nf] = MFMA16(afrag[ks], bfrag[nf][ks], acc[mf][nf], 0, 0, 0);
  }

  int cr = (lane >> 4) * 4;
#pragma unroll
  for (int mf = 0; mf < 4; ++mf) {
#pragma unroll
    for (int r = 0; r < 4; ++r) {
      int m = m0 + mf * 16 + cr + r;
      if (m < M) {
#pragma unroll
        for (int nf = 0; nf < 4; ++nf) {
          int n = n0 + nf * 16 + lr;
          float v = acc[mf][nf][r] + bp[nb + nf * 16 + lr];
          C[(size_t)m * HD + n] = f2bf(v);
        }
      }
    }
  }
}

// ---------------- Fused GATv2 per-node aggregate + LN + ELU (+ MLP) ----------------
// One wave per node; lane l owns channels 4l..4l+3; the 4 sixteen-lane rows = 4 heads
// (per-lane ssum IS the per-head denominator — no cross-row reduce on it).
// NOTE (R5-R9 evidence): pinned at FETCH/1.7 TB/s (L2-fill wall, FETCH at the
// once-per-XCD floor 8x25.6MB); VALU/prefetch changes don't move it. Leave as-is.
template <bool LAST>
__global__ __launch_bounds__(256) void gat_kernel(
    const unsigned short* __restrict__ xlr,
    const float* __restrict__ att, const float* __restrict__ bias,
    const float* __restrict__ gamma, const float* __restrict__ beta,
    const int* __restrict__ row_start, const int* __restrict__ csr_src,
    const float* __restrict__ Wh1, const float* __restrict__ bh1,
    const float* __restrict__ Wh2, const float* __restrict__ bh2,
    void* __restrict__ outp, int N) {
  __shared__ float sh[4][96];
  int wid = threadIdx.x >> 6;
  int lane = threadIdx.x & 63;
  int v = blockIdx.x * 4 + wid;
  if (v >= N) return;
  int c0 = 4 * lane;
  int cc = 4 * (lane & 15);

  uint2 ur = *(const uint2*)&xlr[(size_t)v * HD + 256 + c0];
  float xr0 = ubits(ur.x << 16), xr1 = ubits(ur.x & 0xffff0000u);
  float xr2 = ubits(ur.y << 16), xr3 = ubits(ur.y & 0xffff0000u);
  float4 at4 = *(const float4*)&att[c0];

  float sA = 0.f, sB = 0.f;
  float aA0 = 0.f, aA1 = 0.f, aA2 = 0.f, aA3 = 0.f;
  float aB0 = 0.f, aB1 = 0.f, aB2 = 0.f, aB3 = 0.f;

  int rs = __builtin_amdgcn_readfirstlane(row_start[v]);
  int re = __builtin_amdgcn_readfirstlane(row_start[v + 1]);

  auto fetchi = [&](int i) -> uint2 {
    int ic = i < re ? i : re - 1;  // clamp; masked at accumulate
    int s = csr_src[ic];
    return *(const uint2*)&xlr[(size_t)s * HD + c0];
  };
  auto edge = [&](uint2 u, bool valid, float& ss, float& a0, float& a1,
                  float& a2, float& a3) {
    float x0 = ubits(u.x << 16), x1 = ubits(u.x & 0xffff0000u);
    float x2 = ubits(u.y << 16), x3 = ubits(u.y & 0xffff0000u);
    float t0 = x0 + xr0, t1 = x1 + xr1, t2 = x2 + xr2, t3 = x3 + xr3;
    // sum(att*leaky(t)) = 0.6*sum(att*t) + 0.4*sum(att*|t|)
    float p6 = t0 * at4.x;
    p6 = fmaf(t1, at4.y, p6);
    p6 = fmaf(t2, at4.z, p6);
    p6 = fmaf(t3, at4.w, p6);
    float p4 = fabsf(t0) * at4.x;
    p4 = fmaf(fabsf(t1), at4.y, p4);
    p4 = fmaf(fabsf(t2), at4.z, p4);
    p4 = fmaf(fabsf(t3), at4.w, p4);
    float sc = fmaf(0.4f, p4, 0.6f * p6);
    sc = dpp_add<0x121>(sc);  // row_ror:1
    sc = dpp_add<0x122>(sc);  // row_ror:2
    sc = dpp_add<0x124>(sc);  // row_ror:4
    sc = dpp_add<0x128>(sc);  // row_ror:8 -> 16-lane (per-head) sum
    float p = __expf(sc);  // scores O(1): softmax shift not needed
    p = valid ? p : 0.f;
    ss += p;
    a0 = fmaf(p, t0, a0);  // accumulate p*t; undo +xr after loop
    a1 = fmaf(p, t1, a1);
    a2 = fmaf(p, t2, a2);
    a3 = fmaf(p, t3, a3);
  };

  uint2 A0, A1, A2, A3, B0, B1, B2, B3, C0, C1, C2, C3, D0, D1, D2, D3;
  A0 = fetchi(rs); A1 = fetchi(rs + 1); A2 = fetchi(rs + 2); A3 = fetchi(rs + 3);
  B0 = fetchi(rs + 4); B1 = fetchi(rs + 5); B2 = fetchi(rs + 6); B3 = fetchi(rs + 7);
  C0 = fetchi(rs + 8); C1 = fetchi(rs + 9); C2 = fetchi(rs + 10); C3 = fetchi(rs + 11);
  int b = rs;
  while (true) {
    D0 = fetchi(b + 12); D1 = fetchi(b + 13); D2 = fetchi(b + 14); D3 = fetchi(b + 15);
    edge(A0, true, sA, aA0, aA1, aA2, aA3);
    edge(A1, b + 1 < re, sB, aB0, aB1, aB2, aB3);
    edge(A2, b + 2 < re, sA, aA0, aA1, aA2, aA3);
    edge(A3, b + 3 < re, sB, aB0, aB1, aB2, aB3);
    b += 4;
    if (b >= re) break;
    A0 = fetchi(b + 12); A1 = fetchi(b + 13); A2 = fetchi(b + 14); A3 = fetchi(b + 15);
    edge(B0, true, sA, aA0, aA1, aA2, aA3);
    edge(B1, b + 1 < re, sB, aB0, aB1, aB2, aB3);
    edge(B2, b + 2 < re, sA, aA0, aA1, aA2, aA3);
    edge(B3, b + 3 < re, sB, aB0, aB1, aB2, aB3);
    b += 4;
    if (b >= re) break;
    B0 = fetchi(b + 12); B1 = fetchi(b + 13); B2 = fetchi(b + 14); B3 = fetchi(b + 15);
    edge(C0, true, sA, aA0, aA1, aA2, aA3);
    edge(C1, b + 1 < re, sB, aB0, aB1, aB2, aB3);
    edge(C2, b + 2 < re, sA, aA0, aA1, aA2, aA3);
    edge(C3, b + 3 < re, sB, aB0, aB1, aB2, aB3);
    b += 4;
    if (b >= re) break;
    C0 = fetchi(b + 12); C1 = fetchi(b + 13); C2 = fetchi(b + 14); C3 = fetchi(b + 15);
    edge(D0, true, sA, aA0, aA1, aA2, aA3);
    edge(D1, b + 1 < re, sB, aB0, aB1, aB2, aB3);
    edge(D2, b + 2 < re, sA, aA0, aA1, aA2, aA3);
    edge(D3, b + 3 < re, sB, aB0, aB1, aB2, aB3);
    b += 4;
    if (b >= re) break;
  }

  // per-lane (= per-head) softmax denominator; no cross-row reduction here
  float inv = 1.f / (sA + sB);  // self-loop guarantees > 0

  float am[4] = {aA0 + aB0, aA1 + aB1, aA2 + aB2, aA3 + aB3};
  float xrv[4] = {xr0, xr1, xr2, xr3};
  float hv[4];
#pragma unroll
  for (int j = 0; j < 4; ++j) {
    float a = fmaf(am[j], inv, -xrv[j]);  // normalize per-head, undo +xr
    a += __shfl_xor(a, 16);               // then sum the 4 heads
    a += __shfl_xor(a, 32);
    hv[j] = a;
  }
  float4 bias4 = *(const float4*)&bias[cc];
  hv[0] = 0.25f * hv[0] + bias4.x;
  hv[1] = 0.25f * hv[1] + bias4.y;
  hv[2] = 0.25f * hv[2] + bias4.z;
  hv[3] = 0.25f * hv[3] + bias4.w;
  float psum = hv[0] + hv[1] + hv[2] + hv[3];
  float psq = hv[0] * hv[0] + hv[1] * hv[1] + hv[2] * hv[2] + hv[3] * hv[3];
#pragma unroll
  for (int o = 1; o < 16; o <<= 1) {
    psum += __shfl_xor(psum, o);
    psq += __shfl_xor(psq, o);
  }
  float mean = psum * (1.f / 64.f);
  float var = psq * (1.f / 64.f) - mean * mean;
  float rstd = rsqrtf(var + 1e-5f);
  float4 g4 = *(const float4*)&gamma[cc];
  float4 be4 = *(const float4*)&beta[cc];
  float y[4];
  y[0] = (hv[0] - mean) * rstd * g4.x + be4.x;
  y[1] = (hv[1] - mean) * rstd * g4.y + be4.y;
  y[2] = (hv[2] - mean) * rstd * g4.z + be4.z;
  y[3] = (hv[3] - mean) * rstd * g4.w + be4.w;
#pragma unroll
  for (int j = 0; j < 4; ++j)
    y[j] = y[j] > 0.f ? y[j] : (__expf(y[j]) - 1.f);  // fast ELU (abs err << 4e-3)

  if (!LAST) {
    if (lane < 16) {
      ushort4 o;
      o.x = f2bf(y[0]); o.y = f2bf(y[1]); o.z = f2bf(y[2]); o.w = f2bf(y[3]);
      *(ushort4*)&((unsigned short*)outp)[(size_t)v * HIDC + cc] = o;
    }
  } else {
    float* out = (float*)outp;
    if (lane < 16) {
      sh[wid][cc + 0] = y[0]; sh[wid][cc + 1] = y[1];
      sh[wid][cc + 2] = y[2]; sh[wid][cc + 3] = y[3];
    }
    if (lane < 32) {  // same-wave LDS ordering; waves independent
      float a = bh1[lane];
      const float4* wrow = (const float4*)&Wh1[lane * 64];
#pragma unroll
      for (int k = 0; k < 16; ++k) {
        float4 w4 = wrow[k];
        float4 s4 = *(const float4*)&sh[wid][4 * k];
        a = fmaf(s4.x, w4.x, a); a = fmaf(s4.y, w4.y, a);
        a = fmaf(s4.z, w4.z, a); a = fmaf(s4.w, w4.w, a);
      }
      sh[wid][64 + lane] = fmaxf(a, 0.f);
    }
    if (lane < 2) {
      float o = bh2[lane];
      const float4* wrow = (const float4*)&Wh2[lane * 32];
#pragma unroll
      for (int k = 0; k < 8; ++k) {
        float4 w4 = wrow[k];
        float4 s4 = *(const float4*)&sh[wid][64 + 4 * k];
        o = fmaf(s4.x, w4.x, o); o = fmaf(s4.y, w4.y, o);
        o = fmaf(s4.z, w4.z, o); o = fmaf(s4.w, w4.w, o);
      }
      out[(size_t)v * 2 + lane] = o;
    }
  }
}

// ---------------- launch ----------------
extern "C" void kernel_launch(void* const* d_in, const int* in_sizes, int n_in,
                              void* d_out, int out_size, void* d_ws, size_t ws_size,
                              hipStream_t stream) {
  const float* x = (const float*)d_in[0];
  const int* ei = (const int*)d_in[1];
  const float* Wl1 = (const float*)d_in[2]; const float* bl1 = (const float*)d_in[3];
  const float* Wr1 = (const float*)d_in[4]; const float* br1 = (const float*)d_in[5];
  const float* att1 = (const float*)d_in[6]; const float* bias1 = (const float*)d_in[7];
  const float* Wl2 = (const float*)d_in[8]; const float* bl2 = (const float*)d_in[9];
  const float* Wr2 = (const float*)d_in[10]; const float* br2 = (const float*)d_in[11];
  const float* att2 = (const float*)d_in[12]; const float* bias2 = (const float*)d_in[13];
  const float* g1 = (const float*)d_in[14]; const float* be1 = (const float*)d_in[15];
  const float* g2 = (const float*)d_in[16]; const float* be2 = (const float*)d_in[17];
  const float* Wh1 = (const float*)d_in[18]; const float* bh1 = (const float*)d_in[19];
  const float* Wh2 = (const float*)d_in[20]; const float* bh2 = (const float*)d_in[21];
  float* out = (float*)d_out;

  int N = in_sizes[0] / 128;
  int E = in_sizes[1] / 2;
  int ET = E + N;

  char* ws = (char*)d_ws;
  size_t off = 0;
  auto alloc = [&](size_t bytes) {
    void* p = ws + off;
    off += (bytes + 255) & ~(size_t)255;
    return p;
  };
  unsigned short* xlr = (unsigned short*)alloc((size_t)N * HD * 2);
  unsigned short* xb  = (unsigned short*)alloc((size_t)N * 128 * 2);
  unsigned short* h1b = (unsigned short*)alloc((size_t)N * HIDC * 2);
  unsigned short* Wc1 = (unsigned short*)alloc((size_t)512 * 128 * 2);
  unsigned short* Wc2 = (unsigned short*)alloc((size_t)512 * 64 * 2);
  int* row_start = (int*)alloc((size_t)(N + 1) * 4);
  int* counts = (int*)alloc((size_t)N * 4);
  int* csr = (int*)alloc((size_t)ET * 4);
  int nsb = (N + SCHUNK - 1) / SCHUNK;  // 13 for N=50K (must be <= 64)
  int* bsum = (int*)alloc((size_t)nsb * 4);

  hipMemsetAsync(counts, 0, (size_t)N * 4, stream);

  int eb = (ET + 255) / 256;
  int n4x = N * 128 / 4;
  int pb = (24576 + n4x + 255) / 256;  // weight + x pack blocks
  prep_kernel<<<eb + pb, 256, 0, stream>>>(ei, E, N, eb, counts, x,
                                           Wl1, Wr1, Wl2, Wr2, xb, Wc1, Wc2, n4x);
  scan_p1<<<nsb, 1024, 0, stream>>>(counts, bsum, N);
  scan_p3<<<nsb, 1024, 0, stream>>>(counts, bsum, nsb, row_start, N);
  scatter_kernel<<<eb, 256, 0, stream>>>(ei, E, N, row_start, counts, csr);

  dim3 gg((N + 63) / 64, 2);
  mfma_gemm<128><<<gg, 256, 0, stream>>>(xb, Wc1, bl1, br1, xlr, N);

  int gb = (N + 3) / 4;
  gat_kernel<false><<<gb, 256, 0, stream>>>(xlr, att1, bias1, g1, be1,
                                            row_start, csr, nullptr, nullptr,
                                            nullptr, nullptr, h1b, N);

  mfma_gemm<64><<<gg, 256, 0, stream>>>(h1b, Wc2, bl2, br2, xlr, N);

  gat_kernel<true><<<gb, 256, 0, stream>>>(xlr, att2, bias2, g2, be2,
                                           row_start, csr, Wh1, bh1, Wh2, bh2,
                                           out, N);
}